// Round 16
// baseline (94.164 us; speedup 1.0000x reference)
//
#include <hip/hip_runtime.h>
#include <hip/hip_bf16.h>
#include <math.h>

#define HID    128
#define BATCH  8192
#define NM     16
#define NROWS  (BATCH * NM)      // 131072
#define BN_EPS 1e-5f

#define S1_BLOCKS   256
#define S1_ROWS     (NROWS / S1_BLOCKS)   // 512 rows/block, 1/thread
#define PREP_BLOCKS 32
#define TOT_BLOCKS  (S1_BLOCKS + PREP_BLOCKS)

// workspace layout (floats)
#define WS_PART  0                          // 256 blocks x 32 (27 used)
#define WS_SCALE 8192
#define WS_SHIFT 8320
#define WS_M1    8448                       // M1 = (W1*scale)@Wa1[128:256] (6x128)
#define WS_SV    9216                       // shvec = shift@Wa1[128:256]
#define WS_N1    9344                       // N1 = (W1*scale)@Wc1 (6x128)
#define WS_CV    10112                      // cvec = shift@Wc1 + bc1
#define WS_BW    10240                      // -> bf16 weight region
// bf16 region (ushort):
//   [0     :16384) Wa1T rows 0..127    (c*128+k)   GEMM1
//   [16384 :32768) Wa2T                (c*128+k)   GEMM2
//   [32768 :49152) Wa1T rows 256..383  (c*128+k)   base (hpo part)
//   [49152 :65536) Wc2T                (c*128+k)   critic L2
//   [65536 :69632) W1pack: (W1*scale) hi/lo K=32-packed per col (col*32+k)

// output layout (floats)
#define O1 ((size_t)BATCH * NM)                 // h_pooled
#define O2 (O1 + (size_t)BATCH * HID)           // machine_v

#define G    2          // batch elems per main block (was 4): halves LDS ->
                        // ~21.7 KB -> 7 blocks/CU by LDS, VGPR drops too
#define ROWS (G * NM)   // 32 rows per main block
#define LDH  136        // padded bf16 row stride
#define ZLD  136        // hpo tile row stride
#define LDV  132        // critic tile row stride

typedef __attribute__((ext_vector_type(8))) short short8_t;
typedef __attribute__((ext_vector_type(4))) float f32x4;

#define MFMA16(a, b, c) __builtin_amdgcn_mfma_f32_16x16x32_bf16(a, b, c, 0, 0, 0)

__device__ __forceinline__ unsigned short f2bf(float x) {
    __hip_bfloat16 h = __float2bfloat16(x);
    return *reinterpret_cast<unsigned short*>(&h);
}
__device__ __forceinline__ float bf2f(unsigned short u) {
    __hip_bfloat16 h = *reinterpret_cast<__hip_bfloat16*>(&u);
    return __bfloat162float(h);
}
__device__ __forceinline__ float ftanh(float x) {
    float e = __expf(2.0f * x);
    return 1.0f - 2.0f / (e + 1.0f);
}

// ---------------------------------------------------------------------------
// Kernel 1: moment stats (blocks 0..255, per-block partials, NO atomics)
//         + weight prep (blocks 256+, coalesced-read transposes)
// ---------------------------------------------------------------------------
__global__ __launch_bounds__(512) void stats_prep_kernel(
    const float* __restrict__ fea1,
    const float* __restrict__ Wa1, const float* __restrict__ Wa2,
    const float* __restrict__ Wc2,
    float* __restrict__ ws, unsigned short* __restrict__ wbt)
{
    const int tid = threadIdx.x;
    const int blk = blockIdx.x;

    if (blk >= S1_BLOCKS) {
        // ---- prep: transposed bf16 weight layouts (coalesced reads) ----
        const int idx = (blk - S1_BLOCKS) * 512 + tid;   // 0..16383
        const int k = idx >> 7, c = idx & 127;
        wbt[c * 128 + k]         = f2bf(Wa1[idx]);           // rows 0..127
        wbt[16384 + c * 128 + k] = f2bf(Wa2[idx]);
        wbt[32768 + c * 128 + k] = f2bf(Wa1[32768 + idx]);   // rows 256..383
        wbt[49152 + c * 128 + k] = f2bf(Wc2[idx]);
        return;
    }

    // ---- moment stats: u[6] + S[21] over this block's 512 rows ----
    __shared__ float feaS[S1_ROWS * 6];
    __shared__ float redM[8 * 27];

    const float* src = fea1 + (size_t)blk * (S1_ROWS * 6);
    for (int i = tid; i < S1_ROWS * 6; i += 512) feaS[i] = src[i];
    __syncthreads();

    float f[6];
    #pragma unroll
    for (int j = 0; j < 6; ++j) f[j] = feaS[tid * 6 + j];

    float acc[27];
    #pragma unroll
    for (int j = 0; j < 6; ++j) acc[j] = f[j];
    {
        int idx = 6;
        #pragma unroll
        for (int j = 0; j < 6; ++j)
            #pragma unroll
            for (int k = j; k < 6; ++k) acc[idx++] = f[j] * f[k];
    }
    #pragma unroll
    for (int j = 0; j < 27; ++j) {
        acc[j] += __shfl_xor(acc[j], 1);
        acc[j] += __shfl_xor(acc[j], 2);
        acc[j] += __shfl_xor(acc[j], 4);
        acc[j] += __shfl_xor(acc[j], 8);
        acc[j] += __shfl_xor(acc[j], 16);
        acc[j] += __shfl_xor(acc[j], 32);
    }
    const int wv = tid >> 6;
    if ((tid & 63) == 0) {
        #pragma unroll
        for (int j = 0; j < 27; ++j) redM[wv * 27 + j] = acc[j];
    }
    __syncthreads();
    if (tid < 27) {
        float s = 0.f;
        #pragma unroll
        for (int w2 = 0; w2 < 8; ++w2) s += redM[w2 * 27 + tid];
        ws[WS_PART + blk * 32 + tid] = s;     // plain store, distinct slot
    }
}

// ---------------------------------------------------------------------------
// Kernel 2: finalize, 3 blocks: blk0 = M1+shvec fold, blk1 = N1+cvec fold,
// blk2 = W1pack. Moment reduce + channel stats recomputed redundantly per
// block; folds k-split over 4 thread-groups, coalesced reads, LDS combine.
// ---------------------------------------------------------------------------
__global__ __launch_bounds__(512) void finalize_kernel(
    const float* __restrict__ W1,  const float* __restrict__ Wa1,
    const float* __restrict__ Wc1, const float* __restrict__ bc1,
    const float* __restrict__ gamma, const float* __restrict__ beta,
    float* __restrict__ ws, unsigned short* __restrict__ wbt)
{
    __shared__ double momS[27];
    __shared__ float scS2[HID], shS[HID];
    __shared__ float w1sS[6 * HID];
    __shared__ float partS[4 * 7 * HID];   // 14336 B fold partials

    const int tid = threadIdx.x;
    const int blk = blockIdx.x;            // 0..2

    // ---- reduce 256 partials per moment, in double (redundant per block) ----
    {
        const int j = tid >> 4;        // moment 0..31 (27 used)
        const int l = tid & 15;
        double s = 0.0;
        if (j < 27)
            for (int p = l; p < S1_BLOCKS; p += 16)
                s += (double)ws[WS_PART + p * 32 + j];
        s += __shfl_xor(s, 1);
        s += __shfl_xor(s, 2);
        s += __shfl_xor(s, 4);
        s += __shfl_xor(s, 8);
        if (j < 27 && l == 0) momS[j] = s;
    }
    __syncthreads();

    // ---- channel stats (double quadratic form; only blk 0 writes ws) ----
    if (tid < 128) {
        float wv[6];
        #pragma unroll
        for (int j = 0; j < 6; ++j) wv[j] = W1[j * HID + tid];
        double sum = 0.0, ssq = 0.0;
        #pragma unroll
        for (int j = 0; j < 6; ++j) sum += (double)wv[j] * momS[j];
        {
            int idx = 6;
            #pragma unroll
            for (int j = 0; j < 6; ++j)
                #pragma unroll
                for (int k = j; k < 6; ++k) {
                    double t = (double)wv[j] * (double)wv[k] * momS[idx++];
                    ssq += (j == k) ? t : 2.0 * t;
                }
        }
        const double inv = 1.0 / (double)NROWS;
        double mu  = sum * inv;
        double var = ssq * inv - mu * mu;
        float sc = gamma[tid] * rsqrtf((float)var + BN_EPS);
        float sh = beta[tid] - (float)mu * sc;
        scS2[tid] = sc;
        shS[tid]  = sh;
        if (blk == 0) {
            ws[WS_SCALE + tid] = sc;
            ws[WS_SHIFT + tid] = sh;
        }
    }
    __syncthreads();
    for (int i = tid; i < 6 * HID; i += 512)
        w1sS[i] = W1[i] * scS2[i & 127];
    __syncthreads();

    if (blk == 2) {
        // ---- W1pack: K=32 packing (k0..5=hi, k8..13=hi, k16..21=lo) ----
        for (int idx = tid; idx < HID * 32; idx += 512) {
            const int col = idx >> 5, k = idx & 31;
            unsigned short v = 0;
            int kr = -1; bool lo = false;
            if (k < 6)                    kr = k;
            else if (k >= 8  && k < 14)   kr = k - 8;
            else if (k >= 16 && k < 22) { kr = k - 16; lo = true; }
            if (kr >= 0) {
                const float wv = w1sS[kr * HID + col];
                const unsigned short hi = f2bf(wv);
                v = lo ? f2bf(wv - bf2f(hi)) : hi;
            }
            wbt[65536 + col * 32 + k] = v;
        }
        return;
    }

    // ---- fold: blk0 -> Wa1 rows 128..255 (M1+shvec); blk1 -> Wc1 (N1+cvec) ----
    {
        const float* st = (blk == 0) ? (Wa1 + 16384) : Wc1;
        const int cc = tid & 127;
        const int kq = tid >> 7;           // 0..3
        float a[7] = {0.f, 0.f, 0.f, 0.f, 0.f, 0.f, 0.f};
        for (int k = kq * 32; k < kq * 32 + 32; ++k) {
            const float sv = st[k * 128 + cc];      // coalesced across cc
            #pragma unroll
            for (int j = 0; j < 6; ++j)
                a[j] += w1sS[j * HID + k] * sv;     // LDS broadcast
            a[6] += shS[k] * sv;                    // LDS broadcast
        }
        #pragma unroll
        for (int j = 0; j < 7; ++j)
            partS[(kq * 7 + j) * HID + cc] = a[j];
    }
    __syncthreads();
    if (tid < 128) {
        #pragma unroll
        for (int j = 0; j < 7; ++j) {
            const float v = partS[(0 * 7 + j) * HID + tid]
                          + partS[(1 * 7 + j) * HID + tid]
                          + partS[(2 * 7 + j) * HID + tid]
                          + partS[(3 * 7 + j) * HID + tid];
            if (blk == 0) {
                if (j < 6) ws[WS_M1 + j * HID + tid] = v;
                else       ws[WS_SV + tid] = v;
            } else {
                if (j < 6) ws[WS_N1 + j * HID + tid] = v;
                else       ws[WS_CV + tid] = v + bc1[tid];
            }
        }
    }
}

// ---------------------------------------------------------------------------
// Kernel 3: fused main kernel, G=2 (halved LDS -> ~7 blocks/CU by LDS cap).
// Same structure as G=4 best; g-loops halved; per-element math identical.
// launch_bounds stays (256,4): VGPR cap 128, allocator free (no spill);
// runtime occupancy rises to the LDS limit on its own.
// ---------------------------------------------------------------------------
__global__ __launch_bounds__(256, 4) void main_kernel(
    const float* __restrict__ fea1, const float* __restrict__ hpo,
    const unsigned char* __restrict__ mask,
    const float* __restrict__ W1,
    const float* __restrict__ ba1, const float* __restrict__ ba2,
    const float* __restrict__ Wa3, const float* __restrict__ ba3,
    const float* __restrict__ bc2,
    const float* __restrict__ Wc3, const float* __restrict__ bc3,
    const float* __restrict__ ws, const unsigned short* __restrict__ wbt,
    float* __restrict__ out)
{
    __shared__ __align__(16) unsigned short hmS[ROWS * LDH];  // 8704 B
    __shared__ __align__(16) unsigned short x1S[ROWS * LDH];  // 8704 B (first 768 B alias feaS)
    __shared__ __align__(16) unsigned short zS[G * ZLD];      // 544 B (hpo+hp bf16)
    __shared__ __align__(16) unsigned short v1bS[4 * LDV];    // 1056 B
    __shared__ __align__(16) unsigned short v2bS[4 * LDV];    // 1056 B
    __shared__ float scS[4 * ROWS];                           // 512 B
    __shared__ float fmS[G][8];                               // 64 B (fea row-means)

    float* feaS = (float*)x1S;          // 192 floats (dead before x1S written)

    const int tid = threadIdx.x;
    const int b0  = blockIdx.x * G;

    const int w    = tid >> 6;
    const int lane = tid & 63;
    const int lr   = lane & 15;
    const int lg   = lane >> 4;
    const int n0   = 2 * w;

    const unsigned short* wbt1  = wbt;
    const unsigned short* wbt2  = wbt + 16384;
    const unsigned short* wbtB  = wbt + 32768;
    const unsigned short* wbtC2 = wbt + 49152;
    const unsigned short* wbtW1 = wbt + 65536;

    // ---- stage ----
    for (int i = tid; i < ROWS * 6; i += 256) feaS[i] = fea1[(size_t)b0 * (NM * 6) + i];
    for (int i = tid; i < G * HID; i += 256) {
        const int g = i >> 7, cc = i & 127;
        zS[g * ZLD + cc] = f2bf(hpo[(size_t)b0 * HID + i]);
    }

    // prefetch (consumed right after barrier; short live ranges only)
    short8_t bW[2];
    #pragma unroll
    for (int t = 0; t < 2; ++t)
        bW[t] = *(const short8_t*)(wbtW1 + ((n0 + t) * 16 + lr) * 32 + lg * 8);
    short8_t b1f[2][4];
    #pragma unroll
    for (int t = 0; t < 2; ++t) {
        const unsigned short* br = wbt1 + ((n0 + t) * 16 + lr) * 128 + lg * 8;
        #pragma unroll
        for (int kk = 0; kk < 4; ++kk) b1f[t][kk] = *(const short8_t*)(br + kk * 32);
    }
    const float sh0 = ws[WS_SHIFT + n0 * 16 + lr];
    const float sh1 = ws[WS_SHIFT + (n0 + 1) * 16 + lr];
    __syncthreads();

    // ---- hm = BN(fea @ W1) via ONE split-fp32 MFMA per (g,t) tile ----
    #pragma unroll
    for (int g = 0; g < G; ++g) {
        const float* fr = feaS + (g * 16 + lr) * 6;
        short8_t af;
        #pragma unroll
        for (int j = 0; j < 6; ++j) {
            const float x = fr[j];
            const unsigned short hx = f2bf(x);
            const unsigned short lx = f2bf(x - bf2f(hx));
            unsigned short sel = (lg == 1) ? lx : hx;
            if (lg == 3) sel = 0;
            af[j] = (short)sel;
        }
        af[6] = 0; af[7] = 0;

        #pragma unroll
        for (int t = 0; t < 2; ++t) {
            const float sh = t ? sh1 : sh0;
            f32x4 acc = {sh, sh, sh, sh};
            acc = MFMA16(af, bW[t], acc);
            #pragma unroll
            for (int i = 0; i < 4; ++i)
                hmS[(g * 16 + lg * 4 + i) * LDH + (n0 + t) * 16 + lr] = f2bf(acc[i]);
        }
    }
    // fea row-means (exact fp32), G*6 threads
    if (tid < G * 6) {
        const int g = tid / 6, j = tid % 6;
        float s = 0.f;
        for (int m = 0; m < NM; ++m) s += feaS[(g * 16 + m) * 6 + j];
        fmS[g][j] = s * (1.0f / NM);
    }
    __syncthreads();

    // =================== Phase A: base + critic L1 + hp + GEMM1 ============
    f32x4 accB[2];
    {
        short8_t bBf[2][4];
        #pragma unroll
        for (int t = 0; t < 2; ++t) {
            const unsigned short* br = wbtB + ((n0 + t) * 16 + lr) * 128 + lg * 8;
            #pragma unroll
            for (int kk = 0; kk < 4; ++kk) bBf[t][kk] = *(const short8_t*)(br + kk * 32);
        }
        short8_t za[4];
        const unsigned short* zr = zS + (lr & (G - 1)) * ZLD + lg * 8;
        #pragma unroll
        for (int kk = 0; kk < 4; ++kk) za[kk] = *(const short8_t*)(zr + kk * 32);

        float fm[G][6];
        #pragma unroll
        for (int g = 0; g < G; ++g)
            #pragma unroll
            for (int j = 0; j < 6; ++j) fm[g][j] = fmS[g][j];

        // base = ba1 + shvec + fea_mean@M1 (VALU) + hpo @ Wa1[256:384] (MFMA)
        // A row r holds z[g = r&1]; C row lg*4+i -> g = i&1, so acc[i]=base[i&1]
        #pragma unroll
        for (int t = 0; t < 2; ++t) {
            const int col = (n0 + t) * 16 + lr;
            const float bias = ba1[col] + ws[WS_SV + col];
            float b_[G];
            #pragma unroll
            for (int g = 0; g < G; ++g) {
                float a = bias;
                #pragma unroll
                for (int j = 0; j < 6; ++j) a += fm[g][j] * ws[WS_M1 + j * HID + col];
                b_[g] = a;
            }
            f32x4 acc = {b_[0], b_[1], b_[0], b_[1]};
            acc = MFMA16(za[0], bBf[t][0], acc);
            acc = MFMA16(za[1], bBf[t][1], acc);
            acc = MFMA16(za[2], bBf[t][2], acc);
            acc = MFMA16(za[3], bBf[t][3], acc);
            accB[t] = acc;
        }

        // critic L1 (VALU, g = lg for lg<G): v1 = tanh(fea_mean@N1 + cvec)
        if (lg < G) {
            #pragma unroll
            for (int t = 0; t < 2; ++t) {
                const int col = (n0 + t) * 16 + lr;
                float a = ws[WS_CV + col];
                #pragma unroll
                for (int j = 0; j < 6; ++j) a += fm[lg][j] * ws[WS_N1 + j * HID + col];
                v1bS[lg * LDV + col] = f2bf(ftanh(a));
            }

            // h_pooled output (exact fp32, g = lg)
            #pragma unroll
            for (int t = 0; t < 2; ++t) {
                const int col = (n0 + t) * 16 + lr;
                float a = 0.f;
                #pragma unroll
                for (int j = 0; j < 6; ++j) a += fm[lg][j] * W1[j * HID + col];
                a = a * ws[WS_SCALE + col] + ws[WS_SHIFT + col];
                out[O1 + (size_t)(b0 + lg) * HID + col] = a;
            }
        }
    }

    // prefetch GEMM2 B fragments
    short8_t b2f[2][4];
    #pragma unroll
    for (int t = 0; t < 2; ++t) {
        const unsigned short* br = wbt2 + ((n0 + t) * 16 + lr) * 128 + lg * 8;
        #pragma unroll
        for (int kk = 0; kk < 4; ++kk) b2f[t][kk] = *(const short8_t*)(br + kk * 32);
    }

    // GEMM1 (n-split): x1 = tanh(hm @ Wa1[0:128] + base) -> x1S
    #pragma unroll
    for (int g = 0; g < G; ++g) {
        short8_t ha[4];
        const unsigned short* ar = hmS + (g * 16 + lr) * LDH + lg * 8;
        #pragma unroll
        for (int kk = 0; kk < 4; ++kk) ha[kk] = *(const short8_t*)(ar + kk * 32);
        #pragma unroll
        for (int t = 0; t < 2; ++t) {
            const float bz = accB[t][g];
            f32x4 acc = {bz, bz, bz, bz};
            acc = MFMA16(ha[0], b1f[t][0], acc);
            acc = MFMA16(ha[1], b1f[t][1], acc);
            acc = MFMA16(ha[2], b1f[t][2], acc);
            acc = MFMA16(ha[3], b1f[t][3], acc);
            #pragma unroll
            for (int i = 0; i < 4; ++i)
                x1S[(g * 16 + lg * 4 + i) * LDH + (n0 + t) * 16 + lr] = f2bf(ftanh(acc[i]));
        }
    }
    __syncthreads();

    // =================== Phase B: critic L2 + GEMM2 + score partials =======
    {
        // critic L2 = tanh(v1 @ Wc2 + bc2) -> v2bS (row i holds g = i&1)
        short8_t va[4];
        const unsigned short* vr = v1bS + (lr & (G - 1)) * LDV + lg * 8;
        #pragma unroll
        for (int kk = 0; kk < 4; ++kk) va[kk] = *(const short8_t*)(vr + kk * 32);
        #pragma unroll
        for (int t = 0; t < 2; ++t) {
            const int n = n0 + t;
            const unsigned short* br = wbtC2 + (n * 16 + lr) * 128 + lg * 8;
            const float bi = bc2[n * 16 + lr];
            f32x4 acc = {bi, bi, bi, bi};
            acc = MFMA16(va[0], *(const short8_t*)(br),      acc);
            acc = MFMA16(va[1], *(const short8_t*)(br + 32), acc);
            acc = MFMA16(va[2], *(const short8_t*)(br + 64), acc);
            acc = MFMA16(va[3], *(const short8_t*)(br + 96), acc);
            if (lg == 0) {
                #pragma unroll
                for (int i = 0; i < G; ++i)
                    v2bS[i * LDV + n * 16 + lr] = f2bf(ftanh(acc[i]));
            }
        }

        // GEMM2 (n-split): x2 = tanh(x1 @ Wa2 + ba2); partial scores
        float p[G][4];
        #pragma unroll
        for (int g = 0; g < G; ++g)
            #pragma unroll
            for (int i = 0; i < 4; ++i) p[g][i] = 0.f;

        const float wv0 = Wa3[n0 * 16 + lr];
        const float wv1 = Wa3[(n0 + 1) * 16 + lr];
        const float bi0 = ba2[n0 * 16 + lr];
        const float bi1 = ba2[(n0 + 1) * 16 + lr];
        #pragma unroll
        for (int g = 0; g < G; ++g) {
            short8_t ha[4];
            const unsigned short* ar = x1S + (g * 16 + lr) * LDH + lg * 8;
            #pragma unroll
            for (int kk = 0; kk < 4; ++kk) ha[kk] = *(const short8_t*)(ar + kk * 32);
            #pragma unroll
            for (int t = 0; t < 2; ++t) {
                const float bi = t ? bi1 : bi0;
                f32x4 acc = {bi, bi, bi, bi};
                acc = MFMA16(ha[0], b2f[t][0], acc);
                acc = MFMA16(ha[1], b2f[t][1], acc);
                acc = MFMA16(ha[2], b2f[t][2], acc);
                acc = MFMA16(ha[3], b2f[t][3], acc);
                const float wv = t ? wv1 : wv0;
                #pragma unroll
                for (int i = 0; i < 4; ++i)
                    p[g][i] += ftanh(acc[i]) * wv;
            }
        }
        #pragma unroll
        for (int g = 0; g < G; ++g) {
            #pragma unroll
            for (int i = 0; i < 4; ++i) {
                float v = p[g][i];
                v += __shfl_xor(v, 1);
                v += __shfl_xor(v, 2);
                v += __shfl_xor(v, 4);
                v += __shfl_xor(v, 8);
                if (lr == 0) scS[w * ROWS + g * 16 + lg * 4 + i] = v;
            }
        }
    }
    __syncthreads();

    // ---- softmax (wave w handles g=w, w<G; 16-lane parallel) ----
    if (w < G) {
        const int g = w;
        float s = scS[0 * ROWS + g * 16 + lr] + scS[1 * ROWS + g * 16 + lr]
                + scS[2 * ROWS + g * 16 + lr] + scS[3 * ROWS + g * 16 + lr];
        s = (s + ba3[0]) * 10.0f;
        if (mask[(size_t)(b0 + g) * NM + lr]) s = -INFINITY;
        float mx = s;
        mx = fmaxf(mx, __shfl_xor(mx, 1));
        mx = fmaxf(mx, __shfl_xor(mx, 2));
        mx = fmaxf(mx, __shfl_xor(mx, 4));
        mx = fmaxf(mx, __shfl_xor(mx, 8));
        float e = __expf(s - mx);
        float sum = e;
        sum += __shfl_xor(sum, 1);
        sum += __shfl_xor(sum, 2);
        sum += __shfl_xor(sum, 4);
        sum += __shfl_xor(sum, 8);
        if (lane < NM)
            out[(size_t)(b0 + g) * NM + lr] = e / sum;
    }

    // ---- machine_v (wave w handles g=w, w<G; 64-lane parallel over K) ----
    if (w >= 2 && w - 2 < G) {
        const int g = w - 2;    // waves 2,3 -> g 0,1 (spread work across waves)
        const int k2 = lane * 2;
        float v0 = bf2f(v2bS[g * LDV + k2]);
        float v1 = bf2f(v2bS[g * LDV + k2 + 1]);
        float4 wc = *(const float4*)(Wc3 + k2 * 2);
        float p0 = v0 * wc.x + v1 * wc.z;
        float p1 = v0 * wc.y + v1 * wc.w;
        p0 += __shfl_xor(p0, 1);  p1 += __shfl_xor(p1, 1);
        p0 += __shfl_xor(p0, 2);  p1 += __shfl_xor(p1, 2);
        p0 += __shfl_xor(p0, 4);  p1 += __shfl_xor(p1, 4);
        p0 += __shfl_xor(p0, 8);  p1 += __shfl_xor(p1, 8);
        p0 += __shfl_xor(p0, 16); p1 += __shfl_xor(p1, 16);
        p0 += __shfl_xor(p0, 32); p1 += __shfl_xor(p1, 32);
        if (lane == 0) {
            out[O2 + (size_t)(b0 + g) * 2 + 0] = p0 + bc3[0];
            out[O2 + (size_t)(b0 + g) * 2 + 1] = p1 + bc3[1];
        }
    }
}

// ---------------------------------------------------------------------------
extern "C" void kernel_launch(void* const* d_in, const int* in_sizes, int n_in,
                              void* d_out, int out_size, void* d_ws, size_t ws_size,
                              hipStream_t stream)
{
    const float* fea1  = (const float*)d_in[0];
    const float* hpo   = (const float*)d_in[2];
    const unsigned char* mask = (const unsigned char*)d_in[3];
    const float* W1    = (const float*)d_in[4];
    const float* gamma = (const float*)d_in[8];
    const float* beta  = (const float*)d_in[9];
    const float* Wa1   = (const float*)d_in[10];
    const float* ba1   = (const float*)d_in[11];
    const float* Wa2   = (const float*)d_in[12];
    const float* ba2   = (const float*)d_in[13];
    const float* Wa3   = (const float*)d_in[14];
    const float* ba3   = (const float*)d_in[15];
    const float* Wc1   = (const float*)d_in[16];
    const float* bc1   = (const float*)d_in[17];
    const float* Wc2   = (const float*)d_in[18];
    const float* bc2   = (const float*)d_in[19];
    const float* Wc3   = (const float*)d_in[20];
    const float* bc3   = (const float*)d_in[21];

    float* ws = (float*)d_ws;
    unsigned short* wbt = (unsigned short*)(ws + WS_BW);
    float* out = (float*)d_out;

    stats_prep_kernel<<<TOT_BLOCKS, 512, 0, stream>>>(
        fea1, Wa1, Wa2, Wc2, ws, wbt);
    finalize_kernel<<<3, 512, 0, stream>>>(
        W1, Wa1, Wc1, bc1, gamma, beta, ws, wbt);
    main_kernel<<<BATCH / G, 256, 0, stream>>>(
        fea1, hpo, mask, W1, ba1, ba2, Wa3, ba3,
        bc2, Wc3, bc3, ws, wbt, out);
}

// Round 17
// 68.711 us; speedup vs baseline: 1.3704x; 1.3704x over previous
//
#include <hip/hip_runtime.h>
#include <hip/hip_bf16.h>
#include <math.h>

#define HID    128
#define BATCH  8192
#define NM     16
#define NROWS  (BATCH * NM)      // 131072
#define BN_EPS 1e-5f

#define S1_BLOCKS   256
#define S1_ROWS     (NROWS / S1_BLOCKS)   // 512 rows/block, 1/thread
#define PREP_BLOCKS 32
#define TOT_BLOCKS  (S1_BLOCKS + PREP_BLOCKS)

// workspace layout (floats)
#define WS_PART  0                          // 256 blocks x 32 (27 used)
#define WS_SCALE 8192
#define WS_SHIFT 8320
#define WS_M1    8448                       // M1 = (W1*scale)@Wa1[128:256] (6x128)
#define WS_SV    9216                       // shvec = shift@Wa1[128:256]
#define WS_N1    9344                       // N1 = (W1*scale)@Wc1 (6x128)
#define WS_CV    10112                      // cvec = shift@Wc1 + bc1
#define WS_BW    10240                      // -> bf16 weight region
// bf16 region (ushort):
//   [0     :16384) Wa1T rows 0..127    (c*128+k)   GEMM1
//   [16384 :32768) Wa2T                (c*128+k)   GEMM2
//   [32768 :49152) Wa1T rows 256..383  (c*128+k)   base (hpo part)
//   [49152 :65536) Wc2T                (c*128+k)   critic L2
//   [65536 :69632) W1pack: (W1*scale) hi/lo K=32-packed per col (col*32+k)

// output layout (floats)
#define O1 ((size_t)BATCH * NM)                 // h_pooled
#define O2 (O1 + (size_t)BATCH * HID)           // machine_v

#define G    4
#define ROWS (G * NM)   // 64 rows per main block
#define LDH  136        // padded bf16 row stride
#define ZLD  136        // hpo tile row stride
#define LDV  132        // critic tile row stride

typedef __attribute__((ext_vector_type(8))) short short8_t;
typedef __attribute__((ext_vector_type(4))) float f32x4;

#define MFMA16(a, b, c) __builtin_amdgcn_mfma_f32_16x16x32_bf16(a, b, c, 0, 0, 0)

__device__ __forceinline__ unsigned short f2bf(float x) {
    __hip_bfloat16 h = __float2bfloat16(x);
    return *reinterpret_cast<unsigned short*>(&h);
}
__device__ __forceinline__ float bf2f(unsigned short u) {
    __hip_bfloat16 h = *reinterpret_cast<__hip_bfloat16*>(&u);
    return __bfloat162float(h);
}
__device__ __forceinline__ float ftanh(float x) {
    float e = __expf(2.0f * x);
    return 1.0f - 2.0f / (e + 1.0f);
}

// ---------------------------------------------------------------------------
// Kernel 1: moment stats (blocks 0..255, per-block partials, NO atomics)
//         + weight prep (blocks 256+, coalesced-read transposes)
// ---------------------------------------------------------------------------
__global__ __launch_bounds__(512) void stats_prep_kernel(
    const float* __restrict__ fea1,
    const float* __restrict__ Wa1, const float* __restrict__ Wa2,
    const float* __restrict__ Wc2,
    float* __restrict__ ws, unsigned short* __restrict__ wbt)
{
    const int tid = threadIdx.x;
    const int blk = blockIdx.x;

    if (blk >= S1_BLOCKS) {
        // ---- prep: transposed bf16 weight layouts (coalesced reads) ----
        const int idx = (blk - S1_BLOCKS) * 512 + tid;   // 0..16383
        const int k = idx >> 7, c = idx & 127;
        wbt[c * 128 + k]         = f2bf(Wa1[idx]);           // rows 0..127
        wbt[16384 + c * 128 + k] = f2bf(Wa2[idx]);
        wbt[32768 + c * 128 + k] = f2bf(Wa1[32768 + idx]);   // rows 256..383
        wbt[49152 + c * 128 + k] = f2bf(Wc2[idx]);
        return;
    }

    // ---- moment stats: u[6] + S[21] over this block's 512 rows ----
    __shared__ float feaS[S1_ROWS * 6];
    __shared__ float redM[8 * 27];

    const float* src = fea1 + (size_t)blk * (S1_ROWS * 6);
    for (int i = tid; i < S1_ROWS * 6; i += 512) feaS[i] = src[i];
    __syncthreads();

    float f[6];
    #pragma unroll
    for (int j = 0; j < 6; ++j) f[j] = feaS[tid * 6 + j];

    float acc[27];
    #pragma unroll
    for (int j = 0; j < 6; ++j) acc[j] = f[j];
    {
        int idx = 6;
        #pragma unroll
        for (int j = 0; j < 6; ++j)
            #pragma unroll
            for (int k = j; k < 6; ++k) acc[idx++] = f[j] * f[k];
    }
    #pragma unroll
    for (int j = 0; j < 27; ++j) {
        acc[j] += __shfl_xor(acc[j], 1);
        acc[j] += __shfl_xor(acc[j], 2);
        acc[j] += __shfl_xor(acc[j], 4);
        acc[j] += __shfl_xor(acc[j], 8);
        acc[j] += __shfl_xor(acc[j], 16);
        acc[j] += __shfl_xor(acc[j], 32);
    }
    const int wv = tid >> 6;
    if ((tid & 63) == 0) {
        #pragma unroll
        for (int j = 0; j < 27; ++j) redM[wv * 27 + j] = acc[j];
    }
    __syncthreads();
    if (tid < 27) {
        float s = 0.f;
        #pragma unroll
        for (int w2 = 0; w2 < 8; ++w2) s += redM[w2 * 27 + tid];
        ws[WS_PART + blk * 32 + tid] = s;     // plain store, distinct slot
    }
}

// ---------------------------------------------------------------------------
// Kernel 2: finalize, 3 blocks: blk0 = M1+shvec fold, blk1 = N1+cvec fold,
// blk2 = W1pack. Moment reduce + channel stats recomputed redundantly per
// block; folds k-split over 4 thread-groups, coalesced reads, LDS combine.
// ---------------------------------------------------------------------------
__global__ __launch_bounds__(512) void finalize_kernel(
    const float* __restrict__ W1,  const float* __restrict__ Wa1,
    const float* __restrict__ Wc1, const float* __restrict__ bc1,
    const float* __restrict__ gamma, const float* __restrict__ beta,
    float* __restrict__ ws, unsigned short* __restrict__ wbt)
{
    __shared__ double momS[27];
    __shared__ float scS2[HID], shS[HID];
    __shared__ float w1sS[6 * HID];
    __shared__ float partS[4 * 7 * HID];   // 14336 B fold partials

    const int tid = threadIdx.x;
    const int blk = blockIdx.x;            // 0..2

    // ---- reduce 256 partials per moment, in double (redundant per block) ----
    {
        const int j = tid >> 4;        // moment 0..31 (27 used)
        const int l = tid & 15;
        double s = 0.0;
        if (j < 27)
            for (int p = l; p < S1_BLOCKS; p += 16)
                s += (double)ws[WS_PART + p * 32 + j];
        s += __shfl_xor(s, 1);
        s += __shfl_xor(s, 2);
        s += __shfl_xor(s, 4);
        s += __shfl_xor(s, 8);
        if (j < 27 && l == 0) momS[j] = s;
    }
    __syncthreads();

    // ---- channel stats (double quadratic form; only blk 0 writes ws) ----
    if (tid < 128) {
        float wv[6];
        #pragma unroll
        for (int j = 0; j < 6; ++j) wv[j] = W1[j * HID + tid];
        double sum = 0.0, ssq = 0.0;
        #pragma unroll
        for (int j = 0; j < 6; ++j) sum += (double)wv[j] * momS[j];
        {
            int idx = 6;
            #pragma unroll
            for (int j = 0; j < 6; ++j)
                #pragma unroll
                for (int k = j; k < 6; ++k) {
                    double t = (double)wv[j] * (double)wv[k] * momS[idx++];
                    ssq += (j == k) ? t : 2.0 * t;
                }
        }
        const double inv = 1.0 / (double)NROWS;
        double mu  = sum * inv;
        double var = ssq * inv - mu * mu;
        float sc = gamma[tid] * rsqrtf((float)var + BN_EPS);
        float sh = beta[tid] - (float)mu * sc;
        scS2[tid] = sc;
        shS[tid]  = sh;
        if (blk == 0) {
            ws[WS_SCALE + tid] = sc;
            ws[WS_SHIFT + tid] = sh;
        }
    }
    __syncthreads();
    for (int i = tid; i < 6 * HID; i += 512)
        w1sS[i] = W1[i] * scS2[i & 127];
    __syncthreads();

    if (blk == 2) {
        // ---- W1pack: K=32 packing (k0..5=hi, k8..13=hi, k16..21=lo) ----
        for (int idx = tid; idx < HID * 32; idx += 512) {
            const int col = idx >> 5, k = idx & 31;
            unsigned short v = 0;
            int kr = -1; bool lo = false;
            if (k < 6)                    kr = k;
            else if (k >= 8  && k < 14)   kr = k - 8;
            else if (k >= 16 && k < 22) { kr = k - 16; lo = true; }
            if (kr >= 0) {
                const float wv = w1sS[kr * HID + col];
                const unsigned short hi = f2bf(wv);
                v = lo ? f2bf(wv - bf2f(hi)) : hi;
            }
            wbt[65536 + col * 32 + k] = v;
        }
        return;
    }

    // ---- fold: blk0 -> Wa1 rows 128..255 (M1+shvec); blk1 -> Wc1 (N1+cvec) ----
    {
        const float* st = (blk == 0) ? (Wa1 + 16384) : Wc1;
        const int cc = tid & 127;
        const int kq = tid >> 7;           // 0..3
        float a[7] = {0.f, 0.f, 0.f, 0.f, 0.f, 0.f, 0.f};
        for (int k = kq * 32; k < kq * 32 + 32; ++k) {
            const float sv = st[k * 128 + cc];      // coalesced across cc
            #pragma unroll
            for (int j = 0; j < 6; ++j)
                a[j] += w1sS[j * HID + k] * sv;     // LDS broadcast
            a[6] += shS[k] * sv;                    // LDS broadcast
        }
        #pragma unroll
        for (int j = 0; j < 7; ++j)
            partS[(kq * 7 + j) * HID + cc] = a[j];
    }
    __syncthreads();
    if (tid < 128) {
        #pragma unroll
        for (int j = 0; j < 7; ++j) {
            const float v = partS[(0 * 7 + j) * HID + tid]
                          + partS[(1 * 7 + j) * HID + tid]
                          + partS[(2 * 7 + j) * HID + tid]
                          + partS[(3 * 7 + j) * HID + tid];
            if (blk == 0) {
                if (j < 6) ws[WS_M1 + j * HID + tid] = v;
                else       ws[WS_SV + tid] = v;
            } else {
                if (j < 6) ws[WS_N1 + j * HID + tid] = v;
                else       ws[WS_CV + tid] = v + bc1[tid];
            }
        }
    }
}

// ---------------------------------------------------------------------------
// Kernel 3: fused main kernel (G=4, separate x1S, (256,4) -> VGPR 64, no
// spill). hp-dependent ops folded to rank-6 contractions; hm via split-fp32
// MFMA; N-split GEMMs (weight frags loaded once per block -- the key lever).
// ---------------------------------------------------------------------------
__global__ __launch_bounds__(256, 4) void main_kernel(
    const float* __restrict__ fea1, const float* __restrict__ hpo,
    const unsigned char* __restrict__ mask,
    const float* __restrict__ W1,
    const float* __restrict__ ba1, const float* __restrict__ ba2,
    const float* __restrict__ Wa3, const float* __restrict__ ba3,
    const float* __restrict__ bc2,
    const float* __restrict__ Wc3, const float* __restrict__ bc3,
    const float* __restrict__ ws, const unsigned short* __restrict__ wbt,
    float* __restrict__ out)
{
    __shared__ __align__(16) unsigned short hmS[ROWS * LDH];  // 17408 B
    __shared__ __align__(16) unsigned short x1S[ROWS * LDH];  // 17408 B (first 1536 B alias feaS)
    __shared__ __align__(16) unsigned short zS[G * ZLD];      // 1088 B (hpo only)
    __shared__ __align__(16) unsigned short v1bS[4 * LDV];    // 1056 B
    __shared__ __align__(16) unsigned short v2bS[4 * LDV];    // 1056 B
    __shared__ float scS[4 * ROWS];                           // 1024 B
    __shared__ float fmS[4][8];                               // 128 B (fea row-means)

    float* feaS = (float*)x1S;          // 384 floats (dead before x1S written)

    const int tid = threadIdx.x;
    const int b0  = blockIdx.x * G;

    const int w    = tid >> 6;
    const int lane = tid & 63;
    const int lr   = lane & 15;
    const int lg   = lane >> 4;
    const int n0   = 2 * w;

    const unsigned short* wbt1  = wbt;
    const unsigned short* wbt2  = wbt + 16384;
    const unsigned short* wbtB  = wbt + 32768;
    const unsigned short* wbtC2 = wbt + 49152;
    const unsigned short* wbtW1 = wbt + 65536;

    // ---- stage ----
    for (int i = tid; i < ROWS * 6; i += 256) feaS[i] = fea1[(size_t)b0 * (NM * 6) + i];
    for (int i = tid; i < G * HID; i += 256) {
        const int g = i >> 7, cc = i & 127;
        zS[g * ZLD + cc] = f2bf(hpo[(size_t)b0 * HID + i]);
    }

    // prefetch (consumed right after barrier; short live ranges only)
    short8_t bW[2];
    #pragma unroll
    for (int t = 0; t < 2; ++t)
        bW[t] = *(const short8_t*)(wbtW1 + ((n0 + t) * 16 + lr) * 32 + lg * 8);
    short8_t b1f[2][4];
    #pragma unroll
    for (int t = 0; t < 2; ++t) {
        const unsigned short* br = wbt1 + ((n0 + t) * 16 + lr) * 128 + lg * 8;
        #pragma unroll
        for (int kk = 0; kk < 4; ++kk) b1f[t][kk] = *(const short8_t*)(br + kk * 32);
    }
    const float sh0 = ws[WS_SHIFT + n0 * 16 + lr];
    const float sh1 = ws[WS_SHIFT + (n0 + 1) * 16 + lr];
    __syncthreads();

    // ---- hm = BN(fea @ W1) via ONE split-fp32 MFMA per (g,t) tile ----
    #pragma unroll
    for (int g = 0; g < 4; ++g) {
        const float* fr = feaS + (g * 16 + lr) * 6;
        short8_t af;
        #pragma unroll
        for (int j = 0; j < 6; ++j) {
            const float x = fr[j];
            const unsigned short hx = f2bf(x);
            const unsigned short lx = f2bf(x - bf2f(hx));
            unsigned short sel = (lg == 1) ? lx : hx;
            if (lg == 3) sel = 0;
            af[j] = (short)sel;
        }
        af[6] = 0; af[7] = 0;

        #pragma unroll
        for (int t = 0; t < 2; ++t) {
            const float sh = t ? sh1 : sh0;
            f32x4 acc = {sh, sh, sh, sh};
            acc = MFMA16(af, bW[t], acc);
            #pragma unroll
            for (int i = 0; i < 4; ++i)
                hmS[(g * 16 + lg * 4 + i) * LDH + (n0 + t) * 16 + lr] = f2bf(acc[i]);
        }
    }
    // fea row-means (exact fp32), 24 threads
    if (tid < 24) {
        const int g = tid / 6, j = tid % 6;
        float s = 0.f;
        for (int m = 0; m < NM; ++m) s += feaS[(g * 16 + m) * 6 + j];
        fmS[g][j] = s * (1.0f / NM);
    }
    __syncthreads();

    // =================== Phase A: base + critic L1 + hp + GEMM1 ============
    f32x4 accB[2];
    {
        short8_t bBf[2][4];
        #pragma unroll
        for (int t = 0; t < 2; ++t) {
            const unsigned short* br = wbtB + ((n0 + t) * 16 + lr) * 128 + lg * 8;
            #pragma unroll
            for (int kk = 0; kk < 4; ++kk) bBf[t][kk] = *(const short8_t*)(br + kk * 32);
        }
        short8_t za[4];
        const unsigned short* zr = zS + (lr & 3) * ZLD + lg * 8;
        #pragma unroll
        for (int kk = 0; kk < 4; ++kk) za[kk] = *(const short8_t*)(zr + kk * 32);

        float fm[4][6];
        #pragma unroll
        for (int g = 0; g < 4; ++g)
            #pragma unroll
            for (int j = 0; j < 6; ++j) fm[g][j] = fmS[g][j];

        // base = ba1 + shvec + fea_mean@M1 (VALU) + hpo @ Wa1[256:384] (MFMA)
        #pragma unroll
        for (int t = 0; t < 2; ++t) {
            const int col = (n0 + t) * 16 + lr;
            const float bias = ba1[col] + ws[WS_SV + col];
            float b_[4];
            #pragma unroll
            for (int g = 0; g < 4; ++g) {
                float a = bias;
                #pragma unroll
                for (int j = 0; j < 6; ++j) a += fm[g][j] * ws[WS_M1 + j * HID + col];
                b_[g] = a;
            }
            f32x4 acc = {b_[0], b_[1], b_[2], b_[3]};
            acc = MFMA16(za[0], bBf[t][0], acc);
            acc = MFMA16(za[1], bBf[t][1], acc);
            acc = MFMA16(za[2], bBf[t][2], acc);
            acc = MFMA16(za[3], bBf[t][3], acc);
            accB[t] = acc;
        }

        // critic L1 (VALU, g = lg): v1 = tanh(fea_mean@N1 + cvec)
        #pragma unroll
        for (int t = 0; t < 2; ++t) {
            const int col = (n0 + t) * 16 + lr;
            float a = ws[WS_CV + col];
            #pragma unroll
            for (int j = 0; j < 6; ++j) a += fm[lg][j] * ws[WS_N1 + j * HID + col];
            v1bS[lg * LDV + col] = f2bf(ftanh(a));
        }

        // h_pooled output (exact fp32, g = lg)
        #pragma unroll
        for (int t = 0; t < 2; ++t) {
            const int col = (n0 + t) * 16 + lr;
            float a = 0.f;
            #pragma unroll
            for (int j = 0; j < 6; ++j) a += fm[lg][j] * W1[j * HID + col];
            a = a * ws[WS_SCALE + col] + ws[WS_SHIFT + col];
            out[O1 + (size_t)(b0 + lg) * HID + col] = a;
        }
    }

    // prefetch GEMM2 B fragments
    short8_t b2f[2][4];
    #pragma unroll
    for (int t = 0; t < 2; ++t) {
        const unsigned short* br = wbt2 + ((n0 + t) * 16 + lr) * 128 + lg * 8;
        #pragma unroll
        for (int kk = 0; kk < 4; ++kk) b2f[t][kk] = *(const short8_t*)(br + kk * 32);
    }

    // GEMM1 (n-split): x1 = tanh(hm @ Wa1[0:128] + base) -> x1S
    #pragma unroll
    for (int g = 0; g < 4; ++g) {
        short8_t ha[4];
        const unsigned short* ar = hmS + (g * 16 + lr) * LDH + lg * 8;
        #pragma unroll
        for (int kk = 0; kk < 4; ++kk) ha[kk] = *(const short8_t*)(ar + kk * 32);
        #pragma unroll
        for (int t = 0; t < 2; ++t) {
            const float bz = accB[t][g];
            f32x4 acc = {bz, bz, bz, bz};
            acc = MFMA16(ha[0], b1f[t][0], acc);
            acc = MFMA16(ha[1], b1f[t][1], acc);
            acc = MFMA16(ha[2], b1f[t][2], acc);
            acc = MFMA16(ha[3], b1f[t][3], acc);
            #pragma unroll
            for (int i = 0; i < 4; ++i)
                x1S[(g * 16 + lg * 4 + i) * LDH + (n0 + t) * 16 + lr] = f2bf(ftanh(acc[i]));
        }
    }
    __syncthreads();

    // =================== Phase B: critic L2 + GEMM2 + score partials =======
    {
        // critic L2 = tanh(v1 @ Wc2 + bc2) -> v2bS
        short8_t va[4];
        const unsigned short* vr = v1bS + (lr & 3) * LDV + lg * 8;
        #pragma unroll
        for (int kk = 0; kk < 4; ++kk) va[kk] = *(const short8_t*)(vr + kk * 32);
        #pragma unroll
        for (int t = 0; t < 2; ++t) {
            const int n = n0 + t;
            const unsigned short* br = wbtC2 + (n * 16 + lr) * 128 + lg * 8;
            const float bi = bc2[n * 16 + lr];
            f32x4 acc = {bi, bi, bi, bi};
            acc = MFMA16(va[0], *(const short8_t*)(br),      acc);
            acc = MFMA16(va[1], *(const short8_t*)(br + 32), acc);
            acc = MFMA16(va[2], *(const short8_t*)(br + 64), acc);
            acc = MFMA16(va[3], *(const short8_t*)(br + 96), acc);
            if (lg == 0) {
                #pragma unroll
                for (int i = 0; i < 4; ++i)
                    v2bS[i * LDV + n * 16 + lr] = f2bf(ftanh(acc[i]));
            }
        }

        // GEMM2 (n-split): x2 = tanh(x1 @ Wa2 + ba2); partial scores
        float p[4][4];
        #pragma unroll
        for (int g = 0; g < 4; ++g)
            #pragma unroll
            for (int i = 0; i < 4; ++i) p[g][i] = 0.f;

        const float wv0 = Wa3[n0 * 16 + lr];
        const float wv1 = Wa3[(n0 + 1) * 16 + lr];
        const float bi0 = ba2[n0 * 16 + lr];
        const float bi1 = ba2[(n0 + 1) * 16 + lr];
        #pragma unroll
        for (int g = 0; g < 4; ++g) {
            short8_t ha[4];
            const unsigned short* ar = x1S + (g * 16 + lr) * LDH + lg * 8;
            #pragma unroll
            for (int kk = 0; kk < 4; ++kk) ha[kk] = *(const short8_t*)(ar + kk * 32);
            #pragma unroll
            for (int t = 0; t < 2; ++t) {
                const float bi = t ? bi1 : bi0;
                f32x4 acc = {bi, bi, bi, bi};
                acc = MFMA16(ha[0], b2f[t][0], acc);
                acc = MFMA16(ha[1], b2f[t][1], acc);
                acc = MFMA16(ha[2], b2f[t][2], acc);
                acc = MFMA16(ha[3], b2f[t][3], acc);
                const float wv = t ? wv1 : wv0;
                #pragma unroll
                for (int i = 0; i < 4; ++i)
                    p[g][i] += ftanh(acc[i]) * wv;
            }
        }
        #pragma unroll
        for (int g = 0; g < 4; ++g) {
            #pragma unroll
            for (int i = 0; i < 4; ++i) {
                float v = p[g][i];
                v += __shfl_xor(v, 1);
                v += __shfl_xor(v, 2);
                v += __shfl_xor(v, 4);
                v += __shfl_xor(v, 8);
                if (lr == 0) scS[w * ROWS + g * 16 + lg * 4 + i] = v;
            }
        }
    }
    __syncthreads();

    // ---- softmax (wave w handles g=w; 16-lane parallel) ----
    {
        const int g = w;
        float s = scS[0 * ROWS + g * 16 + lr] + scS[1 * ROWS + g * 16 + lr]
                + scS[2 * ROWS + g * 16 + lr] + scS[3 * ROWS + g * 16 + lr];
        s = (s + ba3[0]) * 10.0f;
        if (mask[(size_t)(b0 + g) * NM + lr]) s = -INFINITY;
        float mx = s;
        mx = fmaxf(mx, __shfl_xor(mx, 1));
        mx = fmaxf(mx, __shfl_xor(mx, 2));
        mx = fmaxf(mx, __shfl_xor(mx, 4));
        mx = fmaxf(mx, __shfl_xor(mx, 8));
        float e = __expf(s - mx);
        float sum = e;
        sum += __shfl_xor(sum, 1);
        sum += __shfl_xor(sum, 2);
        sum += __shfl_xor(sum, 4);
        sum += __shfl_xor(sum, 8);
        if (lane < NM)
            out[(size_t)(b0 + g) * NM + lr] = e / sum;
    }

    // ---- machine_v (wave w handles g=w; 64-lane parallel over K) ----
    {
        const int g = w;
        const int k2 = lane * 2;
        float v0 = bf2f(v2bS[g * LDV + k2]);
        float v1 = bf2f(v2bS[g * LDV + k2 + 1]);
        float4 wc = *(const float4*)(Wc3 + k2 * 2);
        float p0 = v0 * wc.x + v1 * wc.z;
        float p1 = v0 * wc.y + v1 * wc.w;
        p0 += __shfl_xor(p0, 1);  p1 += __shfl_xor(p1, 1);
        p0 += __shfl_xor(p0, 2);  p1 += __shfl_xor(p1, 2);
        p0 += __shfl_xor(p0, 4);  p1 += __shfl_xor(p1, 4);
        p0 += __shfl_xor(p0, 8);  p1 += __shfl_xor(p1, 8);
        p0 += __shfl_xor(p0, 16); p1 += __shfl_xor(p1, 16);
        p0 += __shfl_xor(p0, 32); p1 += __shfl_xor(p1, 32);
        if (lane == 0) {
            out[O2 + (size_t)(b0 + g) * 2 + 0] = p0 + bc3[0];
            out[O2 + (size_t)(b0 + g) * 2 + 1] = p1 + bc3[1];
        }
    }
}

// ---------------------------------------------------------------------------
extern "C" void kernel_launch(void* const* d_in, const int* in_sizes, int n_in,
                              void* d_out, int out_size, void* d_ws, size_t ws_size,
                              hipStream_t stream)
{
    const float* fea1  = (const float*)d_in[0];
    const float* hpo   = (const float*)d_in[2];
    const unsigned char* mask = (const unsigned char*)d_in[3];
    const float* W1    = (const float*)d_in[4];
    const float* gamma = (const float*)d_in[8];
    const float* beta  = (const float*)d_in[9];
    const float* Wa1   = (const float*)d_in[10];
    const float* ba1   = (const float*)d_in[11];
    const float* Wa2   = (const float*)d_in[12];
    const float* ba2   = (const float*)d_in[13];
    const float* Wa3   = (const float*)d_in[14];
    const float* ba3   = (const float*)d_in[15];
    const float* Wc1   = (const float*)d_in[16];
    const float* bc1   = (const float*)d_in[17];
    const float* Wc2   = (const float*)d_in[18];
    const float* bc2   = (const float*)d_in[19];
    const float* Wc3   = (const float*)d_in[20];
    const float* bc3   = (const float*)d_in[21];

    float* ws = (float*)d_ws;
    unsigned short* wbt = (unsigned short*)(ws + WS_BW);
    float* out = (float*)d_out;

    stats_prep_kernel<<<TOT_BLOCKS, 512, 0, stream>>>(
        fea1, Wa1, Wa2, Wc2, ws, wbt);
    finalize_kernel<<<3, 512, 0, stream>>>(
        W1, Wa1, Wc1, bc1, gamma, beta, ws, wbt);
    main_kernel<<<BATCH / G, 256, 0, stream>>>(
        fea1, hpo, mask, W1, ba1, ba2, Wa3, ba3,
        bc2, Wc3, bc3, ws, wbt, out);
}

// Round 18
// 67.622 us; speedup vs baseline: 1.3925x; 1.0161x over previous
//
#include <hip/hip_runtime.h>
#include <hip/hip_bf16.h>
#include <math.h>

#define HID    128
#define BATCH  8192
#define NM     16
#define NROWS  (BATCH * NM)      // 131072
#define BN_EPS 1e-5f

#define S1_BLOCKS   256
#define S1_ROWS     (NROWS / S1_BLOCKS)   // 512 rows/block, 1/thread
#define PREP_BLOCKS 32
#define TOT_BLOCKS  (S1_BLOCKS + PREP_BLOCKS)

// workspace layout (floats)
#define WS_PART  0                          // 256 blocks x 32 (27 used)
#define WS_SCALE 8192
#define WS_SHIFT 8320
#define WS_M1    8448                       // M1 = (W1*scale)@Wa1[128:256] (6x128)
#define WS_SV    9216                       // shvec = shift@Wa1[128:256]
#define WS_N1    9344                       // N1 = (W1*scale)@Wc1 (6x128)
#define WS_CV    10112                      // cvec = shift@Wc1 + bc1
#define WS_BW    10240                      // -> bf16 weight region
// bf16 region (ushort):
//   [0     :16384) Wa1T rows 0..127    (c*128+k)   GEMM1
//   [16384 :32768) Wa2T                (c*128+k)   GEMM2
//   [32768 :49152) Wa1T rows 256..383  (c*128+k)   base (hpo part)
//   [49152 :65536) Wc2T                (c*128+k)   critic L2
//   [65536 :69632) W1pack: (W1*scale) hi/lo K=32-packed per col (col*32+k)

// output layout (floats)
#define O1 ((size_t)BATCH * NM)                 // h_pooled
#define O2 (O1 + (size_t)BATCH * HID)           // machine_v

#define G    4
#define ROWS (G * NM)   // 64 rows per main block
#define LDH  136        // padded bf16 row stride
#define ZLD  136        // hpo tile row stride
#define LDV  132        // critic tile row stride
#define HLD  24         // feaHL row stride (48 B: 2-way conflict-free, 16B-aligned)

typedef __attribute__((ext_vector_type(8))) short short8_t;
typedef __attribute__((ext_vector_type(4))) float f32x4;

#define MFMA16(a, b, c) __builtin_amdgcn_mfma_f32_16x16x32_bf16(a, b, c, 0, 0, 0)

__device__ __forceinline__ unsigned short f2bf(float x) {
    __hip_bfloat16 h = __float2bfloat16(x);
    return *reinterpret_cast<unsigned short*>(&h);
}
__device__ __forceinline__ float bf2f(unsigned short u) {
    __hip_bfloat16 h = *reinterpret_cast<__hip_bfloat16*>(&u);
    return __bfloat162float(h);
}
__device__ __forceinline__ float ftanh(float x) {
    float e = __expf(2.0f * x);
    return 1.0f - 2.0f / (e + 1.0f);
}

// ---------------------------------------------------------------------------
// Kernel 1: moment stats (blocks 0..255, per-block partials, NO atomics)
//         + weight prep (blocks 256+, coalesced-read transposes)
// ---------------------------------------------------------------------------
__global__ __launch_bounds__(512) void stats_prep_kernel(
    const float* __restrict__ fea1,
    const float* __restrict__ Wa1, const float* __restrict__ Wa2,
    const float* __restrict__ Wc2,
    float* __restrict__ ws, unsigned short* __restrict__ wbt)
{
    const int tid = threadIdx.x;
    const int blk = blockIdx.x;

    if (blk >= S1_BLOCKS) {
        // ---- prep: transposed bf16 weight layouts (coalesced reads) ----
        const int idx = (blk - S1_BLOCKS) * 512 + tid;   // 0..16383
        const int k = idx >> 7, c = idx & 127;
        wbt[c * 128 + k]         = f2bf(Wa1[idx]);           // rows 0..127
        wbt[16384 + c * 128 + k] = f2bf(Wa2[idx]);
        wbt[32768 + c * 128 + k] = f2bf(Wa1[32768 + idx]);   // rows 256..383
        wbt[49152 + c * 128 + k] = f2bf(Wc2[idx]);
        return;
    }

    // ---- moment stats: u[6] + S[21] over this block's 512 rows ----
    __shared__ float feaS[S1_ROWS * 6];
    __shared__ float redM[8 * 27];

    const float* src = fea1 + (size_t)blk * (S1_ROWS * 6);
    for (int i = tid; i < S1_ROWS * 6; i += 512) feaS[i] = src[i];
    __syncthreads();

    float f[6];
    #pragma unroll
    for (int j = 0; j < 6; ++j) f[j] = feaS[tid * 6 + j];

    float acc[27];
    #pragma unroll
    for (int j = 0; j < 6; ++j) acc[j] = f[j];
    {
        int idx = 6;
        #pragma unroll
        for (int j = 0; j < 6; ++j)
            #pragma unroll
            for (int k = j; k < 6; ++k) acc[idx++] = f[j] * f[k];
    }
    #pragma unroll
    for (int j = 0; j < 27; ++j) {
        acc[j] += __shfl_xor(acc[j], 1);
        acc[j] += __shfl_xor(acc[j], 2);
        acc[j] += __shfl_xor(acc[j], 4);
        acc[j] += __shfl_xor(acc[j], 8);
        acc[j] += __shfl_xor(acc[j], 16);
        acc[j] += __shfl_xor(acc[j], 32);
    }
    const int wv = tid >> 6;
    if ((tid & 63) == 0) {
        #pragma unroll
        for (int j = 0; j < 27; ++j) redM[wv * 27 + j] = acc[j];
    }
    __syncthreads();
    if (tid < 27) {
        float s = 0.f;
        #pragma unroll
        for (int w2 = 0; w2 < 8; ++w2) s += redM[w2 * 27 + tid];
        ws[WS_PART + blk * 32 + tid] = s;     // plain store, distinct slot
    }
}

// ---------------------------------------------------------------------------
// Kernel 2: finalize, 3 blocks: blk0 = M1+shvec fold, blk1 = N1+cvec fold,
// blk2 = W1pack. Moment reduce + channel stats recomputed redundantly per
// block; folds k-split over 4 thread-groups, coalesced reads, LDS combine.
// ---------------------------------------------------------------------------
__global__ __launch_bounds__(512) void finalize_kernel(
    const float* __restrict__ W1,  const float* __restrict__ Wa1,
    const float* __restrict__ Wc1, const float* __restrict__ bc1,
    const float* __restrict__ gamma, const float* __restrict__ beta,
    float* __restrict__ ws, unsigned short* __restrict__ wbt)
{
    __shared__ double momS[27];
    __shared__ float scS2[HID], shS[HID];
    __shared__ float w1sS[6 * HID];
    __shared__ float partS[4 * 7 * HID];   // 14336 B fold partials

    const int tid = threadIdx.x;
    const int blk = blockIdx.x;            // 0..2

    // ---- reduce 256 partials per moment, in double (redundant per block) ----
    {
        const int j = tid >> 4;        // moment 0..31 (27 used)
        const int l = tid & 15;
        double s = 0.0;
        if (j < 27)
            for (int p = l; p < S1_BLOCKS; p += 16)
                s += (double)ws[WS_PART + p * 32 + j];
        s += __shfl_xor(s, 1);
        s += __shfl_xor(s, 2);
        s += __shfl_xor(s, 4);
        s += __shfl_xor(s, 8);
        if (j < 27 && l == 0) momS[j] = s;
    }
    __syncthreads();

    // ---- channel stats (double quadratic form; only blk 0 writes ws) ----
    if (tid < 128) {
        float wv[6];
        #pragma unroll
        for (int j = 0; j < 6; ++j) wv[j] = W1[j * HID + tid];
        double sum = 0.0, ssq = 0.0;
        #pragma unroll
        for (int j = 0; j < 6; ++j) sum += (double)wv[j] * momS[j];
        {
            int idx = 6;
            #pragma unroll
            for (int j = 0; j < 6; ++j)
                #pragma unroll
                for (int k = j; k < 6; ++k) {
                    double t = (double)wv[j] * (double)wv[k] * momS[idx++];
                    ssq += (j == k) ? t : 2.0 * t;
                }
        }
        const double inv = 1.0 / (double)NROWS;
        double mu  = sum * inv;
        double var = ssq * inv - mu * mu;
        float sc = gamma[tid] * rsqrtf((float)var + BN_EPS);
        float sh = beta[tid] - (float)mu * sc;
        scS2[tid] = sc;
        shS[tid]  = sh;
        if (blk == 0) {
            ws[WS_SCALE + tid] = sc;
            ws[WS_SHIFT + tid] = sh;
        }
    }
    __syncthreads();
    for (int i = tid; i < 6 * HID; i += 512)
        w1sS[i] = W1[i] * scS2[i & 127];
    __syncthreads();

    if (blk == 2) {
        // ---- W1pack: K=32 packing (k0..5=hi, k8..13=hi, k16..21=lo) ----
        for (int idx = tid; idx < HID * 32; idx += 512) {
            const int col = idx >> 5, k = idx & 31;
            unsigned short v = 0;
            int kr = -1; bool lo = false;
            if (k < 6)                    kr = k;
            else if (k >= 8  && k < 14)   kr = k - 8;
            else if (k >= 16 && k < 22) { kr = k - 16; lo = true; }
            if (kr >= 0) {
                const float wv = w1sS[kr * HID + col];
                const unsigned short hi = f2bf(wv);
                v = lo ? f2bf(wv - bf2f(hi)) : hi;
            }
            wbt[65536 + col * 32 + k] = v;
        }
        return;
    }

    // ---- fold: blk0 -> Wa1 rows 128..255 (M1+shvec); blk1 -> Wc1 (N1+cvec) ----
    {
        const float* st = (blk == 0) ? (Wa1 + 16384) : Wc1;
        const int cc = tid & 127;
        const int kq = tid >> 7;           // 0..3
        float a[7] = {0.f, 0.f, 0.f, 0.f, 0.f, 0.f, 0.f};
        for (int k = kq * 32; k < kq * 32 + 32; ++k) {
            const float sv = st[k * 128 + cc];      // coalesced across cc
            #pragma unroll
            for (int j = 0; j < 6; ++j)
                a[j] += w1sS[j * HID + k] * sv;     // LDS broadcast
            a[6] += shS[k] * sv;                    // LDS broadcast
        }
        #pragma unroll
        for (int j = 0; j < 7; ++j)
            partS[(kq * 7 + j) * HID + cc] = a[j];
    }
    __syncthreads();
    if (tid < 128) {
        #pragma unroll
        for (int j = 0; j < 7; ++j) {
            const float v = partS[(0 * 7 + j) * HID + tid]
                          + partS[(1 * 7 + j) * HID + tid]
                          + partS[(2 * 7 + j) * HID + tid]
                          + partS[(3 * 7 + j) * HID + tid];
            if (blk == 0) {
                if (j < 6) ws[WS_M1 + j * HID + tid] = v;
                else       ws[WS_SV + tid] = v;
            } else {
                if (j < 6) ws[WS_N1 + j * HID + tid] = v;
                else       ws[WS_CV + tid] = v + bc1[tid];
            }
        }
    }
}

// ---------------------------------------------------------------------------
// Kernel 3: fused main kernel (G=4, separate x1S, (256,4)). NEW vs R17:
// fea hi/lo bf16 split precomputed ONCE during staging into feaHL
// ([65][24] ushort, row 64 = zeros); hm's A-fragment becomes a single
// ds_read_b128 (pads supply zero k-slots) -- removes ~70 redundant VALU
// ops/thread and a serial convert chain. hm numerics bit-identical.
// ---------------------------------------------------------------------------
__global__ __launch_bounds__(256, 4) void main_kernel(
    const float* __restrict__ fea1, const float* __restrict__ hpo,
    const unsigned char* __restrict__ mask,
    const float* __restrict__ W1,
    const float* __restrict__ ba1, const float* __restrict__ ba2,
    const float* __restrict__ Wa3, const float* __restrict__ ba3,
    const float* __restrict__ bc2,
    const float* __restrict__ Wc3, const float* __restrict__ bc3,
    const float* __restrict__ ws, const unsigned short* __restrict__ wbt,
    float* __restrict__ out)
{
    __shared__ __align__(16) unsigned short hmS[ROWS * LDH];  // 17408 B
    __shared__ __align__(16) unsigned short x1S[ROWS * LDH];  // 17408 B (head aliased below)
    __shared__ __align__(16) unsigned short zS[G * ZLD];      // 1088 B (hpo only)
    __shared__ __align__(16) unsigned short v1bS[4 * LDV];    // 1056 B
    __shared__ __align__(16) unsigned short v2bS[4 * LDV];    // 1056 B
    __shared__ float scS[4 * ROWS];                           // 1024 B
    __shared__ float fmS[4][8];                               // 128 B (fea row-means)

    float* feaS = (float*)x1S;              // 384 floats @ x1S[0:768] (dead before x1S written)
    unsigned short* feaHL = x1S + 768;      // [65][24] ushort @ x1S[768:2328]

    const int tid = threadIdx.x;
    const int b0  = blockIdx.x * G;

    const int w    = tid >> 6;
    const int lane = tid & 63;
    const int lr   = lane & 15;
    const int lg   = lane >> 4;
    const int n0   = 2 * w;

    const unsigned short* wbt1  = wbt;
    const unsigned short* wbt2  = wbt + 16384;
    const unsigned short* wbtB  = wbt + 32768;
    const unsigned short* wbtC2 = wbt + 49152;
    const unsigned short* wbtW1 = wbt + 65536;

    // ---- stage: fea fp32 + precomputed hi/lo bf16 split ----
    for (int i = tid; i < ROWS * 6; i += 256) {
        const float x = fea1[(size_t)b0 * (NM * 6) + i];
        feaS[i] = x;
        const int r = i / 6, j = i - r * 6;
        const unsigned short hx = f2bf(x);
        const unsigned short lx = f2bf(x - bf2f(hx));
        feaHL[r * HLD + j]     = hx;
        feaHL[r * HLD + 8 + j] = lx;
    }
    // zero the pad slots (k6,k7 of each half) + the zero row (row 64)
    if (tid < 64) {
        feaHL[tid * HLD + 6]  = 0;
        feaHL[tid * HLD + 7]  = 0;
        feaHL[tid * HLD + 14] = 0;
        feaHL[tid * HLD + 15] = 0;
    } else if (tid < 80) {
        feaHL[64 * HLD + (tid - 64)] = 0;
    }
    for (int i = tid; i < G * HID; i += 256) {
        const int g = i >> 7, cc = i & 127;
        zS[g * ZLD + cc] = f2bf(hpo[(size_t)b0 * HID + i]);
    }

    // prefetch (consumed right after barrier; short live ranges only)
    short8_t bW[2];
    #pragma unroll
    for (int t = 0; t < 2; ++t)
        bW[t] = *(const short8_t*)(wbtW1 + ((n0 + t) * 16 + lr) * 32 + lg * 8);
    short8_t b1f[2][4];
    #pragma unroll
    for (int t = 0; t < 2; ++t) {
        const unsigned short* br = wbt1 + ((n0 + t) * 16 + lr) * 128 + lg * 8;
        #pragma unroll
        for (int kk = 0; kk < 4; ++kk) b1f[t][kk] = *(const short8_t*)(br + kk * 32);
    }
    const float sh0 = ws[WS_SHIFT + n0 * 16 + lr];
    const float sh1 = ws[WS_SHIFT + (n0 + 1) * 16 + lr];
    __syncthreads();

    // ---- hm = BN(fea @ W1) via ONE split-fp32 MFMA per (g,t) tile;
    //      A-fragment = one ds_read_b128 from precomputed feaHL ----
    const int hloff = (lg == 1) ? 8 : 0;
    #pragma unroll
    for (int g = 0; g < 4; ++g) {
        const int row = (lg == 3) ? 64 : (g * 16 + lr);
        short8_t af = *(const short8_t*)(feaHL + row * HLD + hloff);

        #pragma unroll
        for (int t = 0; t < 2; ++t) {
            const float sh = t ? sh1 : sh0;
            f32x4 acc = {sh, sh, sh, sh};
            acc = MFMA16(af, bW[t], acc);
            #pragma unroll
            for (int i = 0; i < 4; ++i)
                hmS[(g * 16 + lg * 4 + i) * LDH + (n0 + t) * 16 + lr] = f2bf(acc[i]);
        }
    }
    // fea row-means (exact fp32), 24 threads
    if (tid < 24) {
        const int g = tid / 6, j = tid % 6;
        float s = 0.f;
        for (int m = 0; m < NM; ++m) s += feaS[(g * 16 + m) * 6 + j];
        fmS[g][j] = s * (1.0f / NM);
    }
    __syncthreads();

    // =================== Phase A: base + critic L1 + hp + GEMM1 ============
    f32x4 accB[2];
    {
        short8_t bBf[2][4];
        #pragma unroll
        for (int t = 0; t < 2; ++t) {
            const unsigned short* br = wbtB + ((n0 + t) * 16 + lr) * 128 + lg * 8;
            #pragma unroll
            for (int kk = 0; kk < 4; ++kk) bBf[t][kk] = *(const short8_t*)(br + kk * 32);
        }
        short8_t za[4];
        const unsigned short* zr = zS + (lr & 3) * ZLD + lg * 8;
        #pragma unroll
        for (int kk = 0; kk < 4; ++kk) za[kk] = *(const short8_t*)(zr + kk * 32);

        float fm[4][6];
        #pragma unroll
        for (int g = 0; g < 4; ++g)
            #pragma unroll
            for (int j = 0; j < 6; ++j) fm[g][j] = fmS[g][j];

        // base = ba1 + shvec + fea_mean@M1 (VALU) + hpo @ Wa1[256:384] (MFMA)
        #pragma unroll
        for (int t = 0; t < 2; ++t) {
            const int col = (n0 + t) * 16 + lr;
            const float bias = ba1[col] + ws[WS_SV + col];
            float b_[4];
            #pragma unroll
            for (int g = 0; g < 4; ++g) {
                float a = bias;
                #pragma unroll
                for (int j = 0; j < 6; ++j) a += fm[g][j] * ws[WS_M1 + j * HID + col];
                b_[g] = a;
            }
            f32x4 acc = {b_[0], b_[1], b_[2], b_[3]};
            acc = MFMA16(za[0], bBf[t][0], acc);
            acc = MFMA16(za[1], bBf[t][1], acc);
            acc = MFMA16(za[2], bBf[t][2], acc);
            acc = MFMA16(za[3], bBf[t][3], acc);
            accB[t] = acc;
        }

        // critic L1 (VALU, g = lg): v1 = tanh(fea_mean@N1 + cvec)
        #pragma unroll
        for (int t = 0; t < 2; ++t) {
            const int col = (n0 + t) * 16 + lr;
            float a = ws[WS_CV + col];
            #pragma unroll
            for (int j = 0; j < 6; ++j) a += fm[lg][j] * ws[WS_N1 + j * HID + col];
            v1bS[lg * LDV + col] = f2bf(ftanh(a));
        }

        // h_pooled output (exact fp32, g = lg)
        #pragma unroll
        for (int t = 0; t < 2; ++t) {
            const int col = (n0 + t) * 16 + lr;
            float a = 0.f;
            #pragma unroll
            for (int j = 0; j < 6; ++j) a += fm[lg][j] * W1[j * HID + col];
            a = a * ws[WS_SCALE + col] + ws[WS_SHIFT + col];
            out[O1 + (size_t)(b0 + lg) * HID + col] = a;
        }
    }

    // prefetch GEMM2 B fragments
    short8_t b2f[2][4];
    #pragma unroll
    for (int t = 0; t < 2; ++t) {
        const unsigned short* br = wbt2 + ((n0 + t) * 16 + lr) * 128 + lg * 8;
        #pragma unroll
        for (int kk = 0; kk < 4; ++kk) b2f[t][kk] = *(const short8_t*)(br + kk * 32);
    }

    // GEMM1 (n-split): x1 = tanh(hm @ Wa1[0:128] + base) -> x1S
    #pragma unroll
    for (int g = 0; g < 4; ++g) {
        short8_t ha[4];
        const unsigned short* ar = hmS + (g * 16 + lr) * LDH + lg * 8;
        #pragma unroll
        for (int kk = 0; kk < 4; ++kk) ha[kk] = *(const short8_t*)(ar + kk * 32);
        #pragma unroll
        for (int t = 0; t < 2; ++t) {
            const float bz = accB[t][g];
            f32x4 acc = {bz, bz, bz, bz};
            acc = MFMA16(ha[0], b1f[t][0], acc);
            acc = MFMA16(ha[1], b1f[t][1], acc);
            acc = MFMA16(ha[2], b1f[t][2], acc);
            acc = MFMA16(ha[3], b1f[t][3], acc);
            #pragma unroll
            for (int i = 0; i < 4; ++i)
                x1S[(g * 16 + lg * 4 + i) * LDH + (n0 + t) * 16 + lr] = f2bf(ftanh(acc[i]));
        }
    }
    __syncthreads();

    // =================== Phase B: critic L2 + GEMM2 + score partials =======
    {
        // critic L2 = tanh(v1 @ Wc2 + bc2) -> v2bS
        short8_t va[4];
        const unsigned short* vr = v1bS + (lr & 3) * LDV + lg * 8;
        #pragma unroll
        for (int kk = 0; kk < 4; ++kk) va[kk] = *(const short8_t*)(vr + kk * 32);
        #pragma unroll
        for (int t = 0; t < 2; ++t) {
            const int n = n0 + t;
            const unsigned short* br = wbtC2 + (n * 16 + lr) * 128 + lg * 8;
            const float bi = bc2[n * 16 + lr];
            f32x4 acc = {bi, bi, bi, bi};
            acc = MFMA16(va[0], *(const short8_t*)(br),      acc);
            acc = MFMA16(va[1], *(const short8_t*)(br + 32), acc);
            acc = MFMA16(va[2], *(const short8_t*)(br + 64), acc);
            acc = MFMA16(va[3], *(const short8_t*)(br + 96), acc);
            if (lg == 0) {
                #pragma unroll
                for (int i = 0; i < 4; ++i)
                    v2bS[i * LDV + n * 16 + lr] = f2bf(ftanh(acc[i]));
            }
        }

        // GEMM2 (n-split): x2 = tanh(x1 @ Wa2 + ba2); partial scores
        float p[4][4];
        #pragma unroll
        for (int g = 0; g < 4; ++g)
            #pragma unroll
            for (int i = 0; i < 4; ++i) p[g][i] = 0.f;

        const float wv0 = Wa3[n0 * 16 + lr];
        const float wv1 = Wa3[(n0 + 1) * 16 + lr];
        const float bi0 = ba2[n0 * 16 + lr];
        const float bi1 = ba2[(n0 + 1) * 16 + lr];
        #pragma unroll
        for (int g = 0; g < 4; ++g) {
            short8_t ha[4];
            const unsigned short* ar = x1S + (g * 16 + lr) * LDH + lg * 8;
            #pragma unroll
            for (int kk = 0; kk < 4; ++kk) ha[kk] = *(const short8_t*)(ar + kk * 32);
            #pragma unroll
            for (int t = 0; t < 2; ++t) {
                const float bi = t ? bi1 : bi0;
                f32x4 acc = {bi, bi, bi, bi};
                acc = MFMA16(ha[0], b2f[t][0], acc);
                acc = MFMA16(ha[1], b2f[t][1], acc);
                acc = MFMA16(ha[2], b2f[t][2], acc);
                acc = MFMA16(ha[3], b2f[t][3], acc);
                const float wv = t ? wv1 : wv0;
                #pragma unroll
                for (int i = 0; i < 4; ++i)
                    p[g][i] += ftanh(acc[i]) * wv;
            }
        }
        #pragma unroll
        for (int g = 0; g < 4; ++g) {
            #pragma unroll
            for (int i = 0; i < 4; ++i) {
                float v = p[g][i];
                v += __shfl_xor(v, 1);
                v += __shfl_xor(v, 2);
                v += __shfl_xor(v, 4);
                v += __shfl_xor(v, 8);
                if (lr == 0) scS[w * ROWS + g * 16 + lg * 4 + i] = v;
            }
        }
    }
    __syncthreads();

    // ---- softmax (wave w handles g=w; 16-lane parallel) ----
    {
        const int g = w;
        float s = scS[0 * ROWS + g * 16 + lr] + scS[1 * ROWS + g * 16 + lr]
                + scS[2 * ROWS + g * 16 + lr] + scS[3 * ROWS + g * 16 + lr];
        s = (s + ba3[0]) * 10.0f;
        if (mask[(size_t)(b0 + g) * NM + lr]) s = -INFINITY;
        float mx = s;
        mx = fmaxf(mx, __shfl_xor(mx, 1));
        mx = fmaxf(mx, __shfl_xor(mx, 2));
        mx = fmaxf(mx, __shfl_xor(mx, 4));
        mx = fmaxf(mx, __shfl_xor(mx, 8));
        float e = __expf(s - mx);
        float sum = e;
        sum += __shfl_xor(sum, 1);
        sum += __shfl_xor(sum, 2);
        sum += __shfl_xor(sum, 4);
        sum += __shfl_xor(sum, 8);
        if (lane < NM)
            out[(size_t)(b0 + g) * NM + lr] = e / sum;
    }

    // ---- machine_v (wave w handles g=w; 64-lane parallel over K) ----
    {
        const int g = w;
        const int k2 = lane * 2;
        float v0 = bf2f(v2bS[g * LDV + k2]);
        float v1 = bf2f(v2bS[g * LDV + k2 + 1]);
        float4 wc = *(const float4*)(Wc3 + k2 * 2);
        float p0 = v0 * wc.x + v1 * wc.z;
        float p1 = v0 * wc.y + v1 * wc.w;
        p0 += __shfl_xor(p0, 1);  p1 += __shfl_xor(p1, 1);
        p0 += __shfl_xor(p0, 2);  p1 += __shfl_xor(p1, 2);
        p0 += __shfl_xor(p0, 4);  p1 += __shfl_xor(p1, 4);
        p0 += __shfl_xor(p0, 8);  p1 += __shfl_xor(p1, 8);
        p0 += __shfl_xor(p0, 16); p1 += __shfl_xor(p1, 16);
        p0 += __shfl_xor(p0, 32); p1 += __shfl_xor(p1, 32);
        if (lane == 0) {
            out[O2 + (size_t)(b0 + g) * 2 + 0] = p0 + bc3[0];
            out[O2 + (size_t)(b0 + g) * 2 + 1] = p1 + bc3[1];
        }
    }
}

// ---------------------------------------------------------------------------
extern "C" void kernel_launch(void* const* d_in, const int* in_sizes, int n_in,
                              void* d_out, int out_size, void* d_ws, size_t ws_size,
                              hipStream_t stream)
{
    const float* fea1  = (const float*)d_in[0];
    const float* hpo   = (const float*)d_in[2];
    const unsigned char* mask = (const unsigned char*)d_in[3];
    const float* W1    = (const float*)d_in[4];
    const float* gamma = (const float*)d_in[8];
    const float* beta  = (const float*)d_in[9];
    const float* Wa1   = (const float*)d_in[10];
    const float* ba1   = (const float*)d_in[11];
    const float* Wa2   = (const float*)d_in[12];
    const float* ba2   = (const float*)d_in[13];
    const float* Wa3   = (const float*)d_in[14];
    const float* ba3   = (const float*)d_in[15];
    const float* Wc1   = (const float*)d_in[16];
    const float* bc1   = (const float*)d_in[17];
    const float* Wc2   = (const float*)d_in[18];
    const float* bc2   = (const float*)d_in[19];
    const float* Wc3   = (const float*)d_in[20];
    const float* bc3   = (const float*)d_in[21];

    float* ws = (float*)d_ws;
    unsigned short* wbt = (unsigned short*)(ws + WS_BW);
    float* out = (float*)d_out;

    stats_prep_kernel<<<TOT_BLOCKS, 512, 0, stream>>>(
        fea1, Wa1, Wa2, Wc2, ws, wbt);
    finalize_kernel<<<3, 512, 0, stream>>>(
        W1, Wa1, Wc1, bc1, gamma, beta, ws, wbt);
    main_kernel<<<BATCH / G, 256, 0, stream>>>(
        fea1, hpo, mask, W1, ba1, ba2, Wa3, ba3,
        bc2, Wc3, bc3, ws, wbt, out);
}

// Round 20
// 62.986 us; speedup vs baseline: 1.4950x; 1.0736x over previous
//
#include <hip/hip_runtime.h>
#include <hip/hip_bf16.h>
#include <math.h>

#define HID    128
#define BATCH  8192
#define NM     16
#define NROWS  (BATCH * NM)      // 131072
#define BN_EPS 1e-5f

#define S1_BLOCKS   256
#define S1_ROWS     (NROWS / S1_BLOCKS)   // 512 rows/block, 1/thread
#define PREP_BLOCKS 32
#define TOT_BLOCKS  (S1_BLOCKS + PREP_BLOCKS)

// workspace layout (floats)
#define WS_PART  0                          // 256 blocks x 32 (27 used)
#define WS_SCALE 8192
#define WS_SHIFT 8320
#define WS_M1    8448                       // M1 = (W1*scale)@Wa1[128:256] (6x128)
#define WS_SV    9216                       // shvec = shift@Wa1[128:256]
#define WS_N1    9344                       // N1 = (W1*scale)@Wc1 (6x128)
#define WS_CV    10112                      // cvec = shift@Wc1 + bc1
#define WS_BW    10240                      // -> bf16 weight region
// bf16 region (ushort):
//   [0     :16384) Wa1T rows 0..127    (c*128+k)   GEMM1
//   [16384 :32768) Wa2T                (c*128+k)   GEMM2
//   [32768 :49152) Wa1T rows 256..383  (c*128+k)   base (hpo part)
//   [49152 :65536) Wc2T                (c*128+k)   critic L2
//   [65536 :69632) W1pack: (W1*scale) hi/lo K=32-packed per col (col*32+k)

// output layout (floats)
#define O1 ((size_t)BATCH * NM)                 // h_pooled
#define O2 (O1 + (size_t)BATCH * HID)           // machine_v

#define G    8          // batch elems per block; 8 waves (512 thr)
#define ROWS (G * NM)   // 128 rows per main block
#define LDH  136        // padded bf16 row stride
#define ZLD  136        // hpo tile row stride
#define LDV  132        // critic tile row stride
#define HLD  24         // feaHL row stride (48 B)

typedef __attribute__((ext_vector_type(8))) short short8_t;
typedef __attribute__((ext_vector_type(4))) float f32x4;

#define MFMA16(a, b, c) __builtin_amdgcn_mfma_f32_16x16x32_bf16(a, b, c, 0, 0, 0)

__device__ __forceinline__ unsigned short f2bf(float x) {
    __hip_bfloat16 h = __float2bfloat16(x);
    return *reinterpret_cast<unsigned short*>(&h);
}
__device__ __forceinline__ float bf2f(unsigned short u) {
    __hip_bfloat16 h = *reinterpret_cast<__hip_bfloat16*>(&u);
    return __bfloat162float(h);
}
__device__ __forceinline__ float ftanh(float x) {
    float e = __expf(2.0f * x);
    return 1.0f - 2.0f / (e + 1.0f);
}

// ---------------------------------------------------------------------------
// Kernel 1: moment stats (blocks 0..255) + weight prep (blocks 256+)
// ---------------------------------------------------------------------------
__global__ __launch_bounds__(512) void stats_prep_kernel(
    const float* __restrict__ fea1,
    const float* __restrict__ Wa1, const float* __restrict__ Wa2,
    const float* __restrict__ Wc2,
    float* __restrict__ ws, unsigned short* __restrict__ wbt)
{
    const int tid = threadIdx.x;
    const int blk = blockIdx.x;

    if (blk >= S1_BLOCKS) {
        const int idx = (blk - S1_BLOCKS) * 512 + tid;   // 0..16383
        const int k = idx >> 7, c = idx & 127;
        wbt[c * 128 + k]         = f2bf(Wa1[idx]);           // rows 0..127
        wbt[16384 + c * 128 + k] = f2bf(Wa2[idx]);
        wbt[32768 + c * 128 + k] = f2bf(Wa1[32768 + idx]);   // rows 256..383
        wbt[49152 + c * 128 + k] = f2bf(Wc2[idx]);
        return;
    }

    __shared__ float feaS[S1_ROWS * 6];
    __shared__ float redM[8 * 27];

    const float* src = fea1 + (size_t)blk * (S1_ROWS * 6);
    for (int i = tid; i < S1_ROWS * 6; i += 512) feaS[i] = src[i];
    __syncthreads();

    float f[6];
    #pragma unroll
    for (int j = 0; j < 6; ++j) f[j] = feaS[tid * 6 + j];

    float acc[27];
    #pragma unroll
    for (int j = 0; j < 6; ++j) acc[j] = f[j];
    {
        int idx = 6;
        #pragma unroll
        for (int j = 0; j < 6; ++j)
            #pragma unroll
            for (int k = j; k < 6; ++k) acc[idx++] = f[j] * f[k];
    }
    #pragma unroll
    for (int j = 0; j < 27; ++j) {
        acc[j] += __shfl_xor(acc[j], 1);
        acc[j] += __shfl_xor(acc[j], 2);
        acc[j] += __shfl_xor(acc[j], 4);
        acc[j] += __shfl_xor(acc[j], 8);
        acc[j] += __shfl_xor(acc[j], 16);
        acc[j] += __shfl_xor(acc[j], 32);
    }
    const int wv = tid >> 6;
    if ((tid & 63) == 0) {
        #pragma unroll
        for (int j = 0; j < 27; ++j) redM[wv * 27 + j] = acc[j];
    }
    __syncthreads();
    if (tid < 27) {
        float s = 0.f;
        #pragma unroll
        for (int w2 = 0; w2 < 8; ++w2) s += redM[w2 * 27 + tid];
        ws[WS_PART + blk * 32 + tid] = s;
    }
}

// ---------------------------------------------------------------------------
// Kernel 2: finalize, 3 blocks (M1+shvec | N1+cvec | W1pack)
// ---------------------------------------------------------------------------
__global__ __launch_bounds__(512) void finalize_kernel(
    const float* __restrict__ W1,  const float* __restrict__ Wa1,
    const float* __restrict__ Wc1, const float* __restrict__ bc1,
    const float* __restrict__ gamma, const float* __restrict__ beta,
    float* __restrict__ ws, unsigned short* __restrict__ wbt)
{
    __shared__ double momS[27];
    __shared__ float scS2[HID], shS[HID];
    __shared__ float w1sS[6 * HID];
    __shared__ float partS[4 * 7 * HID];

    const int tid = threadIdx.x;
    const int blk = blockIdx.x;            // 0..2

    {
        const int j = tid >> 4;
        const int l = tid & 15;
        double s = 0.0;
        if (j < 27)
            for (int p = l; p < S1_BLOCKS; p += 16)
                s += (double)ws[WS_PART + p * 32 + j];
        s += __shfl_xor(s, 1);
        s += __shfl_xor(s, 2);
        s += __shfl_xor(s, 4);
        s += __shfl_xor(s, 8);
        if (j < 27 && l == 0) momS[j] = s;
    }
    __syncthreads();

    if (tid < 128) {
        float wv[6];
        #pragma unroll
        for (int j = 0; j < 6; ++j) wv[j] = W1[j * HID + tid];
        double sum = 0.0, ssq = 0.0;
        #pragma unroll
        for (int j = 0; j < 6; ++j) sum += (double)wv[j] * momS[j];
        {
            int idx = 6;
            #pragma unroll
            for (int j = 0; j < 6; ++j)
                #pragma unroll
                for (int k = j; k < 6; ++k) {
                    double t = (double)wv[j] * (double)wv[k] * momS[idx++];
                    ssq += (j == k) ? t : 2.0 * t;
                }
        }
        const double inv = 1.0 / (double)NROWS;
        double mu  = sum * inv;
        double var = ssq * inv - mu * mu;
        float sc = gamma[tid] * rsqrtf((float)var + BN_EPS);
        float sh = beta[tid] - (float)mu * sc;
        scS2[tid] = sc;
        shS[tid]  = sh;
        if (blk == 0) {
            ws[WS_SCALE + tid] = sc;
            ws[WS_SHIFT + tid] = sh;
        }
    }
    __syncthreads();
    for (int i = tid; i < 6 * HID; i += 512)
        w1sS[i] = W1[i] * scS2[i & 127];
    __syncthreads();

    if (blk == 2) {
        for (int idx = tid; idx < HID * 32; idx += 512) {
            const int col = idx >> 5, k = idx & 31;
            unsigned short v = 0;
            int kr = -1; bool lo = false;
            if (k < 6)                    kr = k;
            else if (k >= 8  && k < 14)   kr = k - 8;
            else if (k >= 16 && k < 22) { kr = k - 16; lo = true; }
            if (kr >= 0) {
                const float wv = w1sS[kr * HID + col];
                const unsigned short hi = f2bf(wv);
                v = lo ? f2bf(wv - bf2f(hi)) : hi;
            }
            wbt[65536 + col * 32 + k] = v;
        }
        return;
    }

    {
        const float* st = (blk == 0) ? (Wa1 + 16384) : Wc1;
        const int cc = tid & 127;
        const int kq = tid >> 7;
        float a[7] = {0.f, 0.f, 0.f, 0.f, 0.f, 0.f, 0.f};
        for (int k = kq * 32; k < kq * 32 + 32; ++k) {
            const float sv = st[k * 128 + cc];
            #pragma unroll
            for (int j = 0; j < 6; ++j)
                a[j] += w1sS[j * HID + k] * sv;
            a[6] += shS[k] * sv;
        }
        #pragma unroll
        for (int j = 0; j < 7; ++j)
            partS[(kq * 7 + j) * HID + cc] = a[j];
    }
    __syncthreads();
    if (tid < 128) {
        #pragma unroll
        for (int j = 0; j < 7; ++j) {
            const float v = partS[(0 * 7 + j) * HID + tid]
                          + partS[(1 * 7 + j) * HID + tid]
                          + partS[(2 * 7 + j) * HID + tid]
                          + partS[(3 * 7 + j) * HID + tid];
            if (blk == 0) {
                if (j < 6) ws[WS_M1 + j * HID + tid] = v;
                else       ws[WS_SV + tid] = v;
            } else {
                if (j < 6) ws[WS_N1 + j * HID + tid] = v;
                else       ws[WS_CV + tid] = v + bc1[tid];
            }
        }
    }
}

// ---------------------------------------------------------------------------
// Kernel 3: fused main kernel, G=8 x 512 threads. Wave w owns ONE col-tile
// n = w (8 waves x 1 tile = 128 cols -- R19's 2-tiles/wave read OOB).
// Weight fragments per wave HALVED vs G=4 while serving 2x elements ->
// ~3x less weight-load per element. LDS ~80.4 KB -> 2 blocks/CU.
// Base C-rows map g=(lg*4+i)&7; shfl_xor(.,16) transports the other quad.
// ---------------------------------------------------------------------------
__global__ __launch_bounds__(512, 4) void main_kernel(
    const float* __restrict__ fea1, const float* __restrict__ hpo,
    const unsigned char* __restrict__ mask,
    const float* __restrict__ W1,
    const float* __restrict__ ba1, const float* __restrict__ ba2,
    const float* __restrict__ Wa3, const float* __restrict__ ba3,
    const float* __restrict__ bc2,
    const float* __restrict__ Wc3, const float* __restrict__ bc3,
    const float* __restrict__ ws, const unsigned short* __restrict__ wbt,
    float* __restrict__ out)
{
    __shared__ __align__(16) unsigned short hmS[ROWS * LDH];  // 34816 B
    __shared__ __align__(16) unsigned short x1S[ROWS * LDH];  // 34816 B (head aliased)
    __shared__ __align__(16) unsigned short zS[G * ZLD];      // 2176 B
    __shared__ __align__(16) unsigned short v1bS[G * LDV];    // 2112 B
    __shared__ __align__(16) unsigned short v2bS[G * LDV];    // 2112 B
    __shared__ float scS[8 * ROWS];                           // 4096 B
    __shared__ float fmS[G][8];                               // 256 B

    float* feaS = (float*)x1S;              // 768 floats @ x1S[0:1536]
    unsigned short* feaHL = x1S + 1536;     // [129][24] ushort

    const int tid = threadIdx.x;
    const int b0  = blockIdx.x * G;

    const int w    = tid >> 6;     // 0..7 = this wave's col-tile n
    const int lane = tid & 63;
    const int lr   = lane & 15;
    const int lg   = lane >> 4;
    const int col  = w * 16 + lr;  // this lane's output column

    const unsigned short* wbt1  = wbt;
    const unsigned short* wbt2  = wbt + 16384;
    const unsigned short* wbtB  = wbt + 32768;
    const unsigned short* wbtC2 = wbt + 49152;
    const unsigned short* wbtW1 = wbt + 65536;

    // ---- stage: fea fp32 + precomputed hi/lo bf16 split; hpo -> zS ----
    for (int i = tid; i < ROWS * 6; i += 512) {
        const float x = fea1[(size_t)b0 * (NM * 6) + i];
        feaS[i] = x;
        const int r = i / 6, j = i - r * 6;
        const unsigned short hx = f2bf(x);
        const unsigned short lx = f2bf(x - bf2f(hx));
        feaHL[r * HLD + j]     = hx;
        feaHL[r * HLD + 8 + j] = lx;
    }
    if (tid < ROWS) {
        feaHL[tid * HLD + 6]  = 0;
        feaHL[tid * HLD + 7]  = 0;
        feaHL[tid * HLD + 14] = 0;
        feaHL[tid * HLD + 15] = 0;
    } else if (tid < ROWS + 16) {
        feaHL[ROWS * HLD + (tid - ROWS)] = 0;   // zero row
    }
    for (int i = tid; i < G * HID; i += 512) {
        const int g = i >> 7, cc = i & 127;
        zS[g * ZLD + cc] = f2bf(hpo[(size_t)b0 * HID + i]);
    }

    // prefetch (short live ranges): single col-tile n = w
    short8_t bW = *(const short8_t*)(wbtW1 + col * 32 + lg * 8);
    short8_t b1f[4];
    {
        const unsigned short* br = wbt1 + col * 128 + lg * 8;
        #pragma unroll
        for (int kk = 0; kk < 4; ++kk) b1f[kk] = *(const short8_t*)(br + kk * 32);
    }
    const float sh = ws[WS_SHIFT + col];
    __syncthreads();

    // ---- hm = BN(fea @ W1), one split-fp32 MFMA per g; A = 1 ds_read ----
    const int hloff = (lg == 1) ? 8 : 0;
    #pragma unroll
    for (int g = 0; g < G; ++g) {
        const int row = (lg == 3) ? ROWS : (g * 16 + lr);
        short8_t af = *(const short8_t*)(feaHL + row * HLD + hloff);
        f32x4 acc = {sh, sh, sh, sh};
        acc = MFMA16(af, bW, acc);
        #pragma unroll
        for (int i = 0; i < 4; ++i)
            hmS[(g * 16 + lg * 4 + i) * LDH + col] = f2bf(acc[i]);
    }
    // fea row-means (exact fp32), 48 threads
    if (tid < G * 6) {
        const int g = tid / 6, j = tid % 6;
        float s = 0.f;
        for (int m = 0; m < NM; ++m) s += feaS[(g * 16 + m) * 6 + j];
        fmS[g][j] = s * (1.0f / NM);
    }
    __syncthreads();

    // =================== Phase A: base + critic L1 + hp + GEMM1 ============
    f32x4 accB, accBo;
    {
        short8_t za[4];
        const unsigned short* zr = zS + (lr & 7) * ZLD + lg * 8;
        #pragma unroll
        for (int kk = 0; kk < 4; ++kk) za[kk] = *(const short8_t*)(zr + kk * 32);

        // base: acc[i] = base[g=(lg*4+i)&7][col]
        {
            const unsigned short* br = wbtB + col * 128 + lg * 8;
            short8_t bB0 = *(const short8_t*)(br);
            short8_t bB1 = *(const short8_t*)(br + 32);
            short8_t bB2 = *(const short8_t*)(br + 64);
            short8_t bB3 = *(const short8_t*)(br + 96);
            const float bias = ba1[col] + ws[WS_SV + col];
            const int gbase = (lg & 1) ? 4 : 0;     // own quad: g = gbase+i
            float b_[4];
            #pragma unroll
            for (int i = 0; i < 4; ++i) {
                float a = bias;
                #pragma unroll
                for (int j = 0; j < 6; ++j)
                    a += fmS[gbase + i][j] * ws[WS_M1 + j * HID + col];
                b_[i] = a;
            }
            f32x4 acc = {b_[0], b_[1], b_[2], b_[3]};
            acc = MFMA16(za[0], bB0, acc);
            acc = MFMA16(za[1], bB1, acc);
            acc = MFMA16(za[2], bB2, acc);
            acc = MFMA16(za[3], bB3, acc);
            accB = acc;
            #pragma unroll
            for (int i = 0; i < 4; ++i) accBo[i] = __shfl_xor(acc[i], 16);
        }

        // critic L1 (VALU): v1 for g = lg and lg+4
        #pragma unroll
        for (int go = 0; go < 2; ++go) {
            const int g = lg + 4 * go;
            float a = ws[WS_CV + col];
            #pragma unroll
            for (int j = 0; j < 6; ++j) a += fmS[g][j] * ws[WS_N1 + j * HID + col];
            v1bS[g * LDV + col] = f2bf(ftanh(a));
        }

        // h_pooled output (exact fp32) for g = lg and lg+4
        #pragma unroll
        for (int go = 0; go < 2; ++go) {
            const int g = lg + 4 * go;
            float a = 0.f;
            #pragma unroll
            for (int j = 0; j < 6; ++j) a += fmS[g][j] * W1[j * HID + col];
            a = a * ws[WS_SCALE + col] + ws[WS_SHIFT + col];
            out[O1 + (size_t)(b0 + g) * HID + col] = a;
        }
    }

    // prefetch GEMM2 B fragments
    short8_t b2f[4];
    {
        const unsigned short* br = wbt2 + col * 128 + lg * 8;
        #pragma unroll
        for (int kk = 0; kk < 4; ++kk) b2f[kk] = *(const short8_t*)(br + kk * 32);
    }

    // GEMM1 (n-split): x1 = tanh(hm @ Wa1[0:128] + base) -> x1S, g=0..7
    #pragma unroll
    for (int g = 0; g < G; ++g) {
        short8_t ha[4];
        const unsigned short* ar = hmS + (g * 16 + lr) * LDH + lg * 8;
        #pragma unroll
        for (int kk = 0; kk < 4; ++kk) ha[kk] = *(const short8_t*)(ar + kk * 32);
        const float bz = (g < 4)
            ? ((lg & 1) ? accBo[g]     : accB[g])
            : ((lg & 1) ? accB[g - 4]  : accBo[g - 4]);
        f32x4 acc = {bz, bz, bz, bz};
        acc = MFMA16(ha[0], b1f[0], acc);
        acc = MFMA16(ha[1], b1f[1], acc);
        acc = MFMA16(ha[2], b1f[2], acc);
        acc = MFMA16(ha[3], b1f[3], acc);
        #pragma unroll
        for (int i = 0; i < 4; ++i)
            x1S[(g * 16 + lg * 4 + i) * LDH + col] = f2bf(ftanh(acc[i]));
    }
    __syncthreads();

    // =================== Phase B: critic L2 + GEMM2 + score partials =======
    {
        // critic L2: A rows = v1[r&7]; C row lg*4+i -> g=(lg*4+i)&7.
        short8_t va[4];
        const unsigned short* vr = v1bS + (lr & 7) * LDV + lg * 8;
        #pragma unroll
        for (int kk = 0; kk < 4; ++kk) va[kk] = *(const short8_t*)(vr + kk * 32);
        {
            const unsigned short* br = wbtC2 + col * 128 + lg * 8;
            const float bi = bc2[col];
            f32x4 acc = {bi, bi, bi, bi};
            acc = MFMA16(va[0], *(const short8_t*)(br),      acc);
            acc = MFMA16(va[1], *(const short8_t*)(br + 32), acc);
            acc = MFMA16(va[2], *(const short8_t*)(br + 64), acc);
            acc = MFMA16(va[3], *(const short8_t*)(br + 96), acc);
            if (lg < 2) {
                const int gb = lg * 4;
                #pragma unroll
                for (int i = 0; i < 4; ++i)
                    v2bS[(gb + i) * LDV + col] = f2bf(ftanh(acc[i]));
            }
        }

        // GEMM2 (n-split): x2 = tanh(x1 @ Wa2 + ba2); per-g immediate reduce
        const float wv = Wa3[col];
        const float bi = ba2[col];
        #pragma unroll
        for (int g = 0; g < G; ++g) {
            short8_t ha[4];
            const unsigned short* ar = x1S + (g * 16 + lr) * LDH + lg * 8;
            #pragma unroll
            for (int kk = 0; kk < 4; ++kk) ha[kk] = *(const short8_t*)(ar + kk * 32);
            f32x4 acc = {bi, bi, bi, bi};
            acc = MFMA16(ha[0], b2f[0], acc);
            acc = MFMA16(ha[1], b2f[1], acc);
            acc = MFMA16(ha[2], b2f[2], acc);
            acc = MFMA16(ha[3], b2f[3], acc);
            #pragma unroll
            for (int i = 0; i < 4; ++i) {
                float v = ftanh(acc[i]) * wv;
                v += __shfl_xor(v, 1);
                v += __shfl_xor(v, 2);
                v += __shfl_xor(v, 4);
                v += __shfl_xor(v, 8);
                if (lr == 0) scS[w * ROWS + g * 16 + lg * 4 + i] = v;
            }
        }
    }
    __syncthreads();

    // ---- softmax (wave w handles g=w; 16-lane parallel; 8 partials) ----
    {
        const int g = w;
        float s = 0.f;
        #pragma unroll
        for (int w2 = 0; w2 < 8; ++w2)
            s += scS[w2 * ROWS + g * 16 + lr];
        s = (s + ba3[0]) * 10.0f;
        if (mask[(size_t)(b0 + g) * NM + lr]) s = -INFINITY;
        float mx = s;
        mx = fmaxf(mx, __shfl_xor(mx, 1));
        mx = fmaxf(mx, __shfl_xor(mx, 2));
        mx = fmaxf(mx, __shfl_xor(mx, 4));
        mx = fmaxf(mx, __shfl_xor(mx, 8));
        float e = __expf(s - mx);
        float sum = e;
        sum += __shfl_xor(sum, 1);
        sum += __shfl_xor(sum, 2);
        sum += __shfl_xor(sum, 4);
        sum += __shfl_xor(sum, 8);
        if (lane < NM)
            out[(size_t)(b0 + g) * NM + lr] = e / sum;
    }

    // ---- machine_v (wave w handles g=w; 64-lane parallel over K) ----
    {
        const int g = w;
        const int k2 = lane * 2;
        float v0 = bf2f(v2bS[g * LDV + k2]);
        float v1 = bf2f(v2bS[g * LDV + k2 + 1]);
        float4 wc = *(const float4*)(Wc3 + k2 * 2);
        float p0 = v0 * wc.x + v1 * wc.z;
        float p1 = v0 * wc.y + v1 * wc.w;
        p0 += __shfl_xor(p0, 1);  p1 += __shfl_xor(p1, 1);
        p0 += __shfl_xor(p0, 2);  p1 += __shfl_xor(p1, 2);
        p0 += __shfl_xor(p0, 4);  p1 += __shfl_xor(p1, 4);
        p0 += __shfl_xor(p0, 8);  p1 += __shfl_xor(p1, 8);
        p0 += __shfl_xor(p0, 16); p1 += __shfl_xor(p1, 16);
        p0 += __shfl_xor(p0, 32); p1 += __shfl_xor(p1, 32);
        if (lane == 0) {
            out[O2 + (size_t)(b0 + g) * 2 + 0] = p0 + bc3[0];
            out[O2 + (size_t)(b0 + g) * 2 + 1] = p1 + bc3[1];
        }
    }
}

// ---------------------------------------------------------------------------
extern "C" void kernel_launch(void* const* d_in, const int* in_sizes, int n_in,
                              void* d_out, int out_size, void* d_ws, size_t ws_size,
                              hipStream_t stream)
{
    const float* fea1  = (const float*)d_in[0];
    const float* hpo   = (const float*)d_in[2];
    const unsigned char* mask = (const unsigned char*)d_in[3];
    const float* W1    = (const float*)d_in[4];
    const float* gamma = (const float*)d_in[8];
    const float* beta  = (const float*)d_in[9];
    const float* Wa1   = (const float*)d_in[10];
    const float* ba1   = (const float*)d_in[11];
    const float* Wa2   = (const float*)d_in[12];
    const float* ba2   = (const float*)d_in[13];
    const float* Wa3   = (const float*)d_in[14];
    const float* ba3   = (const float*)d_in[15];
    const float* Wc1   = (const float*)d_in[16];
    const float* bc1   = (const float*)d_in[17];
    const float* Wc2   = (const float*)d_in[18];
    const float* bc2   = (const float*)d_in[19];
    const float* Wc3   = (const float*)d_in[20];
    const float* bc3   = (const float*)d_in[21];

    float* ws = (float*)d_ws;
    unsigned short* wbt = (unsigned short*)(ws + WS_BW);
    float* out = (float*)d_out;

    stats_prep_kernel<<<TOT_BLOCKS, 512, 0, stream>>>(
        fea1, Wa1, Wa2, Wc2, ws, wbt);
    finalize_kernel<<<3, 512, 0, stream>>>(
        W1, Wa1, Wc1, bc1, gamma, beta, ws, wbt);
    main_kernel<<<BATCH / G, 512, 0, stream>>>(
        fea1, hpo, mask, W1, ba1, ba2, Wa3, ba3,
        bc2, Wc3, bc3, ws, wbt, out);
}